// Round 1
// baseline (1157.122 us; speedup 1.0000x reference)
//
#include <hip/hip_runtime.h>
#include <math.h>

#define NN 50000
#define EE 800000
#define DD 32

// ---------------- setup kernels ----------------

__global__ __launch_bounds__(256) void k_zero(float* p, int count){
  int i = blockIdx.x*256 + threadIdx.x;
  if (i < count) p[i] = 0.f;
}

__global__ __launch_bounds__(256) void k_hist(const int* __restrict__ node_out,
                                              const float* __restrict__ ew,
                                              float* __restrict__ deg_w,
                                              int* __restrict__ deg_c){
  int e = blockIdx.x*256 + threadIdx.x;
  if (e < EE){
    int o = node_out[e];
    atomicAdd(&deg_w[o], ew[e]);
    atomicAdd(&deg_c[o], 1);
  }
}

__global__ __launch_bounds__(256) void k_logsum(const float* __restrict__ deg_w,
                                                float* __restrict__ logsum){
  __shared__ float sd[256];
  int t = threadIdx.x; int n = blockIdx.x*256 + t;
  float v = (n < NN) ? logf(deg_w[n] + 1.f) : 0.f;
  sd[t] = v; __syncthreads();
  for (int off = 128; off > 0; off >>= 1){
    if (t < off) sd[t] += sd[t+off];
    __syncthreads();
  }
  if (t == 0) atomicAdd(logsum, sd[0]);
}

__global__ __launch_bounds__(256) void k_scan1(const int* __restrict__ deg_c,
                                               int* __restrict__ partials){
  __shared__ int sd[256];
  int t = threadIdx.x; int n = blockIdx.x*256 + t;
  sd[t] = (n < NN) ? deg_c[n] : 0; __syncthreads();
  for (int off = 128; off > 0; off >>= 1){
    if (t < off) sd[t] += sd[t+off];
    __syncthreads();
  }
  if (t == 0) partials[blockIdx.x] = sd[0];
}

__global__ __launch_bounds__(256) void k_scan2(int* __restrict__ partials, int nb,
                                               int* __restrict__ row_start){
  __shared__ int sd[256];
  int t = threadIdx.x;
  int v = (t < nb) ? partials[t] : 0;
  sd[t] = v; __syncthreads();
  for (int off = 1; off < 256; off <<= 1){
    int x = (t >= off) ? sd[t-off] : 0;
    __syncthreads();
    sd[t] += x;
    __syncthreads();
  }
  if (t < nb) partials[t] = sd[t] - v;   // exclusive
  if (t == 0) row_start[NN] = EE;
}

__global__ __launch_bounds__(256) void k_scan3(const int* __restrict__ deg_c,
                                               const int* __restrict__ partials,
                                               int* __restrict__ row_start,
                                               int* __restrict__ cursor){
  __shared__ int sd[256];
  int t = threadIdx.x; int n = blockIdx.x*256 + t;
  int v = (n < NN) ? deg_c[n] : 0;
  sd[t] = v; __syncthreads();
  for (int off = 1; off < 256; off <<= 1){
    int x = (t >= off) ? sd[t-off] : 0;
    __syncthreads();
    sd[t] += x;
    __syncthreads();
  }
  if (n < NN){
    int rs = partials[blockIdx.x] + sd[t] - v;  // exclusive
    row_start[n] = rs; cursor[n] = rs;
  }
}

__global__ __launch_bounds__(256) void k_fillcsr(const int* __restrict__ node_in,
                                                 const int* __restrict__ node_out,
                                                 const float* __restrict__ ew,
                                                 int* __restrict__ cursor,
                                                 int* __restrict__ csr_src,
                                                 float* __restrict__ csr_w){
  int e = blockIdx.x*256 + threadIdx.x;
  if (e < EE){
    int o = node_out[e];
    int pos = atomicAdd(&cursor[o], 1);
    csr_src[pos] = node_in[e];
    csr_w[pos]   = ew[e];
  }
}

__global__ __launch_bounds__(256) void k_scales(const float* __restrict__ deg_w,
                                                const float* __restrict__ logsum,
                                                float* __restrict__ scale_arr,
                                                float* __restrict__ inv_arr){
  int n = blockIdx.x*256 + threadIdx.x;
  if (n < NN){
    float mean = *logsum / (float)NN;
    float s = logf(deg_w[n] + 1.f) / mean;
    scale_arr[n] = s;
    inv_arr[n]   = 1.f / fmaxf(s, 0.01f);
  }
}

// rel_input per layer (6x32) and query-part of final MLP (64)
__global__ __launch_bounds__(256) void k_prep(const float* __restrict__ qw,
                                              const float* __restrict__ rel_W,
                                              const float* __restrict__ rel_b,
                                              const float* __restrict__ W1,
                                              const float* __restrict__ b1,
                                              float* __restrict__ rel6,
                                              float* __restrict__ qc){
  int t = threadIdx.x;
  if (t < 192){
    int l = t >> 5, j = t & 31;
    float s = rel_b[t];
    for (int d = 0; d < 32; ++d) s += qw[d] * rel_W[l*1024 + d*32 + j];
    rel6[t] = s;
  } else if (t < 256){
    int j = t - 192;
    float s = b1[j];
    for (int k = 0; k < 32; ++k) s += qw[k] * W1[(32+k)*64 + j];
    qc[j] = s;
  }
}

__global__ __launch_bounds__(256) void k_init_h(const int* __restrict__ hidx,
                                                float* __restrict__ h,
                                                float* __restrict__ hT){
  int i = blockIdx.x*256 + threadIdx.x;
  int hv = *hidx;
  if (i < NN*DD){
    h[i]  = ((i >> 5) == hv) ? 0.f : 100.f;   // row-major: n = i/32
    int n2 = i % NN;                           // transposed: n = i % N
    hT[i] = (n2 == hv) ? 0.f : 100.f;
  }
}

// t[n] = dot(h[n], rel_layer5) for msg_score
__global__ __launch_bounds__(256) void k_dot(const float* __restrict__ h,
                                             const float* __restrict__ rel6,
                                             float* __restrict__ tdot){
  int n0 = blockIdx.x*256 + threadIdx.x;
  int n = (n0 < NN) ? n0 : NN-1;
  const float* relr = rel6 + 5*32;
  float s = 0.f;
  #pragma unroll
  for (int d = 0; d < 32; ++d) s += h[n*32 + d] * relr[d];
  if (n0 < NN) tdot[n0] = s;
}

// ---------------- per-layer aggregation ----------------
// 32 lanes per node (lane = dim). Aggregates S1=sum(w*h), S2=sum(w*h^2),
// M=max(w*h), m=min(w*h) over in-edges; rel applied afterwards (h>=0, so
// max(rel*w*h) = rel>=0 ? rel*M : rel*m). Self-loop boundary row appended
// raw (no rel). Writes statsT[k'][n] (k' = d*4 + {mean,max,min,std}).
template<bool PRED>
__global__ __launch_bounds__(256) void k_agg(const float* __restrict__ h,
                                             const float* __restrict__ rel6,
                                             const int* __restrict__ row_start,
                                             const int* __restrict__ csr_src,
                                             const float* __restrict__ csr_w,
                                             const int* __restrict__ hidx,
                                             const float* __restrict__ tdot,
                                             float* __restrict__ statsT,
                                             float* __restrict__ pred_out,
                                             int l){
  int tid = threadIdx.x;
  int g = tid >> 5, lane = tid & 31;
  int n = blockIdx.x*8 + g;              // 6250*8 == 50000 exactly
  int s0 = row_start[n], s1 = row_start[n+1];
  float S1 = 0.f, S2 = 0.f, M = -INFINITY, m = INFINITY;
  float best = -INFINITY; int bi = NN;
  for (int e = s0; e < s1; ++e){
    int src  = csr_src[e];
    float w  = csr_w[e];
    float hv = h[src*32 + lane];
    float wm = w * hv;
    S1 += wm; S2 += wm * hv;
    M = fmaxf(M, wm); m = fminf(m, wm);
    if (PRED){
      float scv = w * tdot[src];
      if (scv > best){ best = scv; bi = src; }
      else if (scv == best && src < bi) bi = src;
    }
  }
  int hv0 = *hidx;
  float bnd = (n == hv0) ? 0.f : 100.f;
  float rel = rel6[l*32 + lane];
  int deg = s1 - s0;
  float mx, mn;
  if (deg > 0){
    float em = (rel >= 0.f) ? rel*M : rel*m;
    float en = (rel >= 0.f) ? rel*m : rel*M;
    mx = fmaxf(em, bnd); mn = fminf(en, bnd);
  } else { mx = bnd; mn = bnd; }
  float cnt  = (float)(deg + 1);
  float mean = (rel*S1 + bnd) / cnt;
  float sq   = (rel*rel*S2 + bnd*bnd) / cnt;
  float sd   = sqrtf(fmaxf(sq - mean*mean, 1e-6f));

  if (PRED){
    float ss = (n == hv0) ? 0.f : 3200.f;   // sum of boundary row, w=1
    if (ss > best){ best = ss; bi = n; }
    else if (ss == best && n < bi) bi = n;
    if (lane == 0) pred_out[n] = (float)bi;
  }

  __shared__ float lds[8][129];
  lds[g][lane*4+0] = mean;
  lds[g][lane*4+1] = mx;
  lds[g][lane*4+2] = mn;
  lds[g][lane*4+3] = sd;
  __syncthreads();
  int nbase = blockIdx.x*8;
  for (int idx = tid; idx < 1024; idx += 256){
    int kp = idx >> 3, cc = idx & 7;
    statsT[kp*NN + nbase + cc] = lds[cc][kp];
  }
}

// ---------------- per-layer linear ----------------
// node-per-lane, W rows via wave-uniform (scalar) loads, x via coalesced
// transposed streams. k-dim split over the block's 4 waves, LDS combine.
__global__ __launch_bounds__(256) void k_lin(const float* __restrict__ hT,
                                             const float* __restrict__ statsT,
                                             const float* __restrict__ lin_W,
                                             const float* __restrict__ lin_b,
                                             const float* __restrict__ scale_arr,
                                             const float* __restrict__ inv_arr,
                                             float* __restrict__ h_next,
                                             float* __restrict__ hT_next,
                                             int l){
  const float* Wl = lin_W + (size_t)l * 13312;   // 416*32
  int tid = threadIdx.x;
  int wid = tid >> 6, lane = tid & 63;
  int n0 = blockIdx.x*64 + lane;
  int n = (n0 < NN) ? n0 : NN-1;
  float sc = scale_arr[n], iv = inv_arr[n];
  float acc[32];
  #pragma unroll
  for (int j = 0; j < 32; ++j) acc[j] = 0.f;

  if (wid == 0){
    for (int k = 0; k < 32; ++k){
      float xv = hT[k*NN + n];
      const float* wr = Wl + k*32;
      #pragma unroll
      for (int j = 0; j < 32; ++j) acc[j] += xv * wr[j];
    }
  }
  // stats k' ranges per wave: balanced fma counts
  int k0 = (wid == 0) ? 0  : (wid == 1) ? 24 : (wid == 2) ? 59 : 94;
  int k1 = (wid == 0) ? 24 : (wid == 1) ? 59 : (wid == 2) ? 94 : 128;
  for (int kp = k0; kp < k1; ++kp){
    float f = statsT[kp*NN + n];
    int d = kp >> 2, c = kp & 3;
    const float* wr = Wl + (32 + d*12 + c*3)*32;
    float f1 = f*sc, f2 = f*iv;
    #pragma unroll
    for (int j = 0; j < 32; ++j)
      acc[j] += f*wr[j] + f1*wr[32+j] + f2*wr[64+j];
  }

  __shared__ float red[4][64][33];
  #pragma unroll
  for (int j = 0; j < 32; ++j) red[wid][lane][j] = acc[j];
  __syncthreads();

  int ln = tid >> 2, dbase = (tid & 3) * 8;
  int nn0 = blockIdx.x*64 + ln;
  if (nn0 < NN){
    float sv[8];
    #pragma unroll
    for (int j = 0; j < 8; ++j){
      int dp = dbase + j;
      float v = red[0][ln][dp] + red[1][ln][dp] + red[2][ln][dp] + red[3][ln][dp];
      v += lin_b[l*32 + dp];
      sv[j] = fmaxf(v, 0.f);
    }
    #pragma unroll
    for (int j = 0; j < 8; ++j) h_next[nn0*32 + dbase + j] = sv[j];
    #pragma unroll
    for (int j = 0; j < 8; ++j) hT_next[(dbase+j)*NN + nn0] = sv[j];
  }
}

// ---------------- final MLP ----------------
__global__ __launch_bounds__(256) void k_mlp(const float* __restrict__ hT,
                                             const float* __restrict__ qc,
                                             const float* __restrict__ W1,
                                             const float* __restrict__ W2,
                                             const float* __restrict__ b2,
                                             float* __restrict__ out_score){
  int n0 = blockIdx.x*256 + threadIdx.x;
  int n = (n0 < NN) ? n0 : NN-1;
  float acc[64];
  #pragma unroll
  for (int j = 0; j < 64; ++j) acc[j] = qc[j];
  for (int k = 0; k < 32; ++k){
    float xv = hT[k*NN + n];
    const float* wr = W1 + k*64;
    #pragma unroll
    for (int j = 0; j < 64; ++j) acc[j] += xv * wr[j];
  }
  float s = b2[0];
  #pragma unroll
  for (int j = 0; j < 64; ++j) s += fmaxf(acc[j], 0.f) * W2[j];
  if (n0 < NN) out_score[n0] = s;
}

// ---------------- host launch ----------------
extern "C" void kernel_launch(void* const* d_in, const int* in_sizes, int n_in,
                              void* d_out, int out_size, void* d_ws, size_t ws_size,
                              hipStream_t stream){
  const int*   node_in  = (const int*)d_in[0];
  const int*   node_out = (const int*)d_in[1];
  const float* ew       = (const float*)d_in[2];
  const int*   hidx     = (const int*)d_in[3];
  const float* qw       = (const float*)d_in[4];
  const float* rel_W    = (const float*)d_in[5];
  const float* rel_b    = (const float*)d_in[6];
  const float* lin_W    = (const float*)d_in[7];
  const float* lin_b    = (const float*)d_in[8];
  const float* W1       = (const float*)d_in[9];
  const float* b1       = (const float*)d_in[10];
  const float* W2       = (const float*)d_in[11];
  const float* b2       = (const float*)d_in[12];
  float* out_score = (float*)d_out;
  float* out_pred  = out_score + NN;

  char* w = (char*)d_ws;
  size_t off = 0;
  auto take = [&](size_t bytes)->char*{
    char* p = w + off;
    off = (off + bytes + 255) & ~(size_t)255;
    return p;
  };
  // contiguous zero block: deg_w (N f) | deg_c (N i) | logsum (64 f)
  float* deg_w   = (float*)take((size_t)(2*NN + 64) * 4);
  int*   deg_c   = (int*)(deg_w + NN);
  float* logsum  = (float*)(deg_c + NN);
  int*   row_start = (int*)take((size_t)(NN+1)*4);
  int*   cursor    = (int*)take((size_t)NN*4);
  int*   partials  = (int*)take(256*4);
  float* rel6      = (float*)take(192*4);
  float* qc        = (float*)take(64*4);
  float* scale_arr = (float*)take((size_t)NN*4);
  float* inv_arr   = (float*)take((size_t)NN*4);
  float* tdot      = (float*)take((size_t)NN*4);
  int*   csr_src   = (int*)take((size_t)EE*4);
  float* csr_w     = (float*)take((size_t)EE*4);
  float* h_a       = (float*)take((size_t)NN*32*4);
  float* hT_a      = (float*)take((size_t)NN*32*4);
  float* h_b       = (float*)take((size_t)NN*32*4);
  float* hT_b      = (float*)take((size_t)NN*32*4);
  float* statsT    = (float*)take((size_t)NN*128*4);

  int zc = 2*NN + 64;
  int nb = (NN + 255) / 256;   // 196
  k_zero   <<<(zc+255)/256, 256, 0, stream>>>(deg_w, zc);
  k_hist   <<<(EE+255)/256, 256, 0, stream>>>(node_out, ew, deg_w, deg_c);
  k_logsum <<<nb, 256, 0, stream>>>(deg_w, logsum);
  k_scan1  <<<nb, 256, 0, stream>>>(deg_c, partials);
  k_scan2  <<<1, 256, 0, stream>>>(partials, nb, row_start);
  k_scan3  <<<nb, 256, 0, stream>>>(deg_c, partials, row_start, cursor);
  k_fillcsr<<<(EE+255)/256, 256, 0, stream>>>(node_in, node_out, ew, cursor, csr_src, csr_w);
  k_scales <<<nb, 256, 0, stream>>>(deg_w, logsum, scale_arr, inv_arr);
  k_prep   <<<1, 256, 0, stream>>>(qw, rel_W, rel_b, W1, b1, rel6, qc);
  k_init_h <<<(NN*DD+255)/256, 256, 0, stream>>>(hidx, h_a, hT_a);

  float* hc = h_a;  float* hTc = hT_a;
  float* hn = h_b;  float* hTn = hT_b;
  for (int l = 0; l < 6; ++l){
    if (l == 5){
      k_dot<<<nb, 256, 0, stream>>>(hc, rel6, tdot);
      k_agg<true><<<NN/8, 256, 0, stream>>>(hc, rel6, row_start, csr_src, csr_w,
                                            hidx, tdot, statsT, out_pred, l);
    } else {
      k_agg<false><<<NN/8, 256, 0, stream>>>(hc, rel6, row_start, csr_src, csr_w,
                                             hidx, tdot, statsT, out_pred, l);
    }
    k_lin<<<(NN+63)/64, 256, 0, stream>>>(hTc, statsT, lin_W, lin_b,
                                          scale_arr, inv_arr, hn, hTn, l);
    float* t1 = hc;  hc = hn;  hn = t1;
    float* t2 = hTc; hTc = hTn; hTn = t2;
  }
  k_mlp<<<nb, 256, 0, stream>>>(hTc, qc, W1, W2, b2, out_score);
}

// Round 2
// 823.408 us; speedup vs baseline: 1.4053x; 1.4053x over previous
//
#include <hip/hip_runtime.h>
#include <math.h>

#define NN 50000
#define EE 800000
#define DD 32

// ---------------- setup kernels ----------------

__global__ __launch_bounds__(256) void k_zero(float* p, int count){
  int i = blockIdx.x*256 + threadIdx.x;
  if (i < count) p[i] = 0.f;
}

__global__ __launch_bounds__(256) void k_hist(const int* __restrict__ node_out,
                                              const float* __restrict__ ew,
                                              float* __restrict__ deg_w,
                                              int* __restrict__ deg_c){
  int e = blockIdx.x*256 + threadIdx.x;
  if (e < EE){
    int o = node_out[e];
    atomicAdd(&deg_w[o], ew[e]);
    atomicAdd(&deg_c[o], 1);
  }
}

__global__ __launch_bounds__(256) void k_logsum(const float* __restrict__ deg_w,
                                                float* __restrict__ logsum){
  __shared__ float sd[256];
  int t = threadIdx.x; int n = blockIdx.x*256 + t;
  float v = (n < NN) ? logf(deg_w[n] + 1.f) : 0.f;
  sd[t] = v; __syncthreads();
  for (int off = 128; off > 0; off >>= 1){
    if (t < off) sd[t] += sd[t+off];
    __syncthreads();
  }
  if (t == 0) atomicAdd(logsum, sd[0]);
}

__global__ __launch_bounds__(256) void k_scan1(const int* __restrict__ deg_c,
                                               int* __restrict__ partials){
  __shared__ int sd[256];
  int t = threadIdx.x; int n = blockIdx.x*256 + t;
  sd[t] = (n < NN) ? deg_c[n] : 0; __syncthreads();
  for (int off = 128; off > 0; off >>= 1){
    if (t < off) sd[t] += sd[t+off];
    __syncthreads();
  }
  if (t == 0) partials[blockIdx.x] = sd[0];
}

__global__ __launch_bounds__(256) void k_scan2(int* __restrict__ partials, int nb,
                                               int* __restrict__ row_start){
  __shared__ int sd[256];
  int t = threadIdx.x;
  int v = (t < nb) ? partials[t] : 0;
  sd[t] = v; __syncthreads();
  for (int off = 1; off < 256; off <<= 1){
    int x = (t >= off) ? sd[t-off] : 0;
    __syncthreads();
    sd[t] += x;
    __syncthreads();
  }
  if (t < nb) partials[t] = sd[t] - v;   // exclusive
  if (t == 0) row_start[NN] = EE;
}

__global__ __launch_bounds__(256) void k_scan3(const int* __restrict__ deg_c,
                                               const int* __restrict__ partials,
                                               int* __restrict__ row_start,
                                               int* __restrict__ cursor){
  __shared__ int sd[256];
  int t = threadIdx.x; int n = blockIdx.x*256 + t;
  int v = (n < NN) ? deg_c[n] : 0;
  sd[t] = v; __syncthreads();
  for (int off = 1; off < 256; off <<= 1){
    int x = (t >= off) ? sd[t-off] : 0;
    __syncthreads();
    sd[t] += x;
    __syncthreads();
  }
  if (n < NN){
    int rs = partials[blockIdx.x] + sd[t] - v;  // exclusive
    row_start[n] = rs; cursor[n] = rs;
  }
}

__global__ __launch_bounds__(256) void k_fillcsr(const int* __restrict__ node_in,
                                                 const int* __restrict__ node_out,
                                                 const float* __restrict__ ew,
                                                 int* __restrict__ cursor,
                                                 int* __restrict__ csr_src,
                                                 float* __restrict__ csr_w){
  int e = blockIdx.x*256 + threadIdx.x;
  if (e < EE){
    int o = node_out[e];
    int pos = atomicAdd(&cursor[o], 1);
    csr_src[pos] = node_in[e];
    csr_w[pos]   = ew[e];
  }
}

__global__ __launch_bounds__(256) void k_scales(const float* __restrict__ deg_w,
                                                const float* __restrict__ logsum,
                                                float* __restrict__ scale_arr,
                                                float* __restrict__ inv_arr){
  int n = blockIdx.x*256 + threadIdx.x;
  if (n < NN){
    float mean = *logsum / (float)NN;
    float s = logf(deg_w[n] + 1.f) / mean;
    scale_arr[n] = s;
    inv_arr[n]   = 1.f / fmaxf(s, 0.01f);
  }
}

// rel_input per layer (6x32) and query-part of final MLP (64)
__global__ __launch_bounds__(256) void k_prep(const float* __restrict__ qw,
                                              const float* __restrict__ rel_W,
                                              const float* __restrict__ rel_b,
                                              const float* __restrict__ W1,
                                              const float* __restrict__ b1,
                                              float* __restrict__ rel6,
                                              float* __restrict__ qc){
  int t = threadIdx.x;
  if (t < 192){
    int l = t >> 5, j = t & 31;
    float s = rel_b[t];
    for (int d = 0; d < 32; ++d) s += qw[d] * rel_W[l*1024 + d*32 + j];
    rel6[t] = s;
  } else if (t < 256){
    int j = t - 192;
    float s = b1[j];
    for (int k = 0; k < 32; ++k) s += qw[k] * W1[(32+k)*64 + j];
    qc[j] = s;
  }
}

__global__ __launch_bounds__(256) void k_init_h(const int* __restrict__ hidx,
                                                float* __restrict__ h,
                                                float* __restrict__ hT){
  int i = blockIdx.x*256 + threadIdx.x;
  int hv = *hidx;
  if (i < NN*DD){
    h[i]  = ((i >> 5) == hv) ? 0.f : 100.f;   // row-major: n = i/32
    int n2 = i % NN;                           // transposed: n = i % N
    hT[i] = (n2 == hv) ? 0.f : 100.f;
  }
}

// t[n] = dot(h[n], rel_layer5) for msg_score
__global__ __launch_bounds__(256) void k_dot(const float* __restrict__ h,
                                             const float* __restrict__ rel6,
                                             float* __restrict__ tdot){
  int n0 = blockIdx.x*256 + threadIdx.x;
  int n = (n0 < NN) ? n0 : NN-1;
  const float* relr = rel6 + 5*32;
  float s = 0.f;
  #pragma unroll
  for (int d = 0; d < 32; ++d) s += h[n*32 + d] * relr[d];
  if (n0 < NN) tdot[n0] = s;
}

// ---------------- per-layer aggregation ----------------
// 32 lanes per node (lane = dim). Aggregates S1=sum(w*h), S2=sum(w*h^2),
// M=max(w*h), m=min(w*h) over in-edges; rel applied afterwards (h>=0, so
// max(rel*w*h) = rel>=0 ? rel*M : rel*m). Self-loop boundary row appended
// raw (no rel). Writes statsT[k'][n] (k' = d*4 + {mean,max,min,std}).
template<bool PRED>
__global__ __launch_bounds__(256) void k_agg(const float* __restrict__ h,
                                             const float* __restrict__ rel6,
                                             const int* __restrict__ row_start,
                                             const int* __restrict__ csr_src,
                                             const float* __restrict__ csr_w,
                                             const int* __restrict__ hidx,
                                             const float* __restrict__ tdot,
                                             float* __restrict__ statsT,
                                             float* __restrict__ pred_out,
                                             int l){
  int tid = threadIdx.x;
  int g = tid >> 5, lane = tid & 31;
  int n = blockIdx.x*8 + g;              // 6250*8 == 50000 exactly
  int s0 = row_start[n], s1 = row_start[n+1];
  float S1 = 0.f, S2 = 0.f, M = -INFINITY, m = INFINITY;
  float best = -INFINITY; int bi = NN;
  for (int e = s0; e < s1; ++e){
    int src  = csr_src[e];
    float w  = csr_w[e];
    float hv = h[src*32 + lane];
    float wm = w * hv;
    S1 += wm; S2 += wm * hv;
    M = fmaxf(M, wm); m = fminf(m, wm);
    if (PRED){
      float scv = w * tdot[src];
      if (scv > best){ best = scv; bi = src; }
      else if (scv == best && src < bi) bi = src;
    }
  }
  int hv0 = *hidx;
  float bnd = (n == hv0) ? 0.f : 100.f;
  float rel = rel6[l*32 + lane];
  int deg = s1 - s0;
  float mx, mn;
  if (deg > 0){
    float em = (rel >= 0.f) ? rel*M : rel*m;
    float en = (rel >= 0.f) ? rel*m : rel*M;
    mx = fmaxf(em, bnd); mn = fminf(en, bnd);
  } else { mx = bnd; mn = bnd; }
  float cnt  = (float)(deg + 1);
  float mean = (rel*S1 + bnd) / cnt;
  float sq   = (rel*rel*S2 + bnd*bnd) / cnt;
  float sd   = sqrtf(fmaxf(sq - mean*mean, 1e-6f));

  if (PRED){
    float ss = (n == hv0) ? 0.f : 3200.f;   // sum of boundary row, w=1
    if (ss > best){ best = ss; bi = n; }
    else if (ss == best && n < bi) bi = n;
    if (lane == 0) pred_out[n] = (float)bi;
  }

  __shared__ float lds[8][129];
  lds[g][lane*4+0] = mean;
  lds[g][lane*4+1] = mx;
  lds[g][lane*4+2] = mn;
  lds[g][lane*4+3] = sd;
  __syncthreads();
  int nbase = blockIdx.x*8;
  for (int idx = tid; idx < 1024; idx += 256){
    int kp = idx >> 3, cc = idx & 7;
    statsT[kp*NN + nbase + cc] = lds[cc][kp];
  }
}

// ---------------- per-layer linear ----------------
// j-split: each wave computes 8 of 32 output dims for the block's 64 nodes,
// full K=416. j0 forced wave-scalar via readfirstlane so every W address is
// provably uniform -> s_load (scalar cache). No LDS, no cross-wave reduce.
__global__ __launch_bounds__(256) void k_lin(const float* __restrict__ hT,
                                             const float* __restrict__ statsT,
                                             const float* __restrict__ lin_W,
                                             const float* __restrict__ lin_b,
                                             const float* __restrict__ scale_arr,
                                             const float* __restrict__ inv_arr,
                                             float* __restrict__ h_next,
                                             float* __restrict__ hT_next,
                                             int l){
  const float* Wl = lin_W + (size_t)l * 13312;   // 416*32
  int tid = threadIdx.x;
  int lane = tid & 63;
  int j0 = __builtin_amdgcn_readfirstlane((tid >> 6) * 8);  // 0,8,16,24
  int n0 = blockIdx.x*64 + lane;
  int n = (n0 < NN) ? n0 : NN-1;
  float sc = scale_arr[n], iv = inv_arr[n];
  float acc[8];
  #pragma unroll
  for (int j = 0; j < 8; ++j) acc[j] = lin_b[l*32 + j0 + j];

  // h part: rows 0..32
  for (int k = 0; k < 32; ++k){
    float xv = hT[k*NN + n];
    const float* wr = Wl + k*32 + j0;
    #pragma unroll
    for (int j = 0; j < 8; ++j) acc[j] += xv * wr[j];
  }
  // stats part: kp = d*4 + c -> W rows 32 + d*12 + c*3 + {0,1,2}
  for (int kp = 0; kp < 128; ++kp){
    float f = statsT[kp*NN + n];
    int d = kp >> 2, c = kp & 3;
    const float* wr = Wl + (32 + d*12 + c*3)*32 + j0;
    float f1 = f*sc, f2 = f*iv;
    #pragma unroll
    for (int j = 0; j < 8; ++j)
      acc[j] += f*wr[j] + f1*wr[32+j] + f2*wr[64+j];
  }

  if (n0 < NN){
    #pragma unroll
    for (int j = 0; j < 8; ++j){
      float v = fmaxf(acc[j], 0.f);
      h_next[n0*32 + j0 + j] = v;
      hT_next[(j0+j)*NN + n0] = v;
    }
  }
}

// ---------------- final MLP ----------------
__global__ __launch_bounds__(256) void k_mlp(const float* __restrict__ hT,
                                             const float* __restrict__ qc,
                                             const float* __restrict__ W1,
                                             const float* __restrict__ W2,
                                             const float* __restrict__ b2,
                                             float* __restrict__ out_score){
  int n0 = blockIdx.x*256 + threadIdx.x;
  int n = (n0 < NN) ? n0 : NN-1;
  float acc[64];
  #pragma unroll
  for (int j = 0; j < 64; ++j) acc[j] = qc[j];
  for (int k = 0; k < 32; ++k){
    float xv = hT[k*NN + n];
    const float* wr = W1 + k*64;
    #pragma unroll
    for (int j = 0; j < 64; ++j) acc[j] += xv * wr[j];
  }
  float s = b2[0];
  #pragma unroll
  for (int j = 0; j < 64; ++j) s += fmaxf(acc[j], 0.f) * W2[j];
  if (n0 < NN) out_score[n0] = s;
}

// ---------------- host launch ----------------
extern "C" void kernel_launch(void* const* d_in, const int* in_sizes, int n_in,
                              void* d_out, int out_size, void* d_ws, size_t ws_size,
                              hipStream_t stream){
  const int*   node_in  = (const int*)d_in[0];
  const int*   node_out = (const int*)d_in[1];
  const float* ew       = (const float*)d_in[2];
  const int*   hidx     = (const int*)d_in[3];
  const float* qw       = (const float*)d_in[4];
  const float* rel_W    = (const float*)d_in[5];
  const float* rel_b    = (const float*)d_in[6];
  const float* lin_W    = (const float*)d_in[7];
  const float* lin_b    = (const float*)d_in[8];
  const float* W1       = (const float*)d_in[9];
  const float* b1       = (const float*)d_in[10];
  const float* W2       = (const float*)d_in[11];
  const float* b2       = (const float*)d_in[12];
  float* out_score = (float*)d_out;
  float* out_pred  = out_score + NN;

  char* w = (char*)d_ws;
  size_t off = 0;
  auto take = [&](size_t bytes)->char*{
    char* p = w + off;
    off = (off + bytes + 255) & ~(size_t)255;
    return p;
  };
  // contiguous zero block: deg_w (N f) | deg_c (N i) | logsum (64 f)
  float* deg_w   = (float*)take((size_t)(2*NN + 64) * 4);
  int*   deg_c   = (int*)(deg_w + NN);
  float* logsum  = (float*)(deg_c + NN);
  int*   row_start = (int*)take((size_t)(NN+1)*4);
  int*   cursor    = (int*)take((size_t)NN*4);
  int*   partials  = (int*)take(256*4);
  float* rel6      = (float*)take(192*4);
  float* qc        = (float*)take(64*4);
  float* scale_arr = (float*)take((size_t)NN*4);
  float* inv_arr   = (float*)take((size_t)NN*4);
  float* tdot      = (float*)take((size_t)NN*4);
  int*   csr_src   = (int*)take((size_t)EE*4);
  float* csr_w     = (float*)take((size_t)EE*4);
  float* h_a       = (float*)take((size_t)NN*32*4);
  float* hT_a      = (float*)take((size_t)NN*32*4);
  float* h_b       = (float*)take((size_t)NN*32*4);
  float* hT_b      = (float*)take((size_t)NN*32*4);
  float* statsT    = (float*)take((size_t)NN*128*4);

  int zc = 2*NN + 64;
  int nb = (NN + 255) / 256;   // 196
  k_zero   <<<(zc+255)/256, 256, 0, stream>>>(deg_w, zc);
  k_hist   <<<(EE+255)/256, 256, 0, stream>>>(node_out, ew, deg_w, deg_c);
  k_logsum <<<nb, 256, 0, stream>>>(deg_w, logsum);
  k_scan1  <<<nb, 256, 0, stream>>>(deg_c, partials);
  k_scan2  <<<1, 256, 0, stream>>>(partials, nb, row_start);
  k_scan3  <<<nb, 256, 0, stream>>>(deg_c, partials, row_start, cursor);
  k_fillcsr<<<(EE+255)/256, 256, 0, stream>>>(node_in, node_out, ew, cursor, csr_src, csr_w);
  k_scales <<<nb, 256, 0, stream>>>(deg_w, logsum, scale_arr, inv_arr);
  k_prep   <<<1, 256, 0, stream>>>(qw, rel_W, rel_b, W1, b1, rel6, qc);
  k_init_h <<<(NN*DD+255)/256, 256, 0, stream>>>(hidx, h_a, hT_a);

  float* hc = h_a;  float* hTc = hT_a;
  float* hn = h_b;  float* hTn = hT_b;
  for (int l = 0; l < 6; ++l){
    if (l == 5){
      k_dot<<<nb, 256, 0, stream>>>(hc, rel6, tdot);
      k_agg<true><<<NN/8, 256, 0, stream>>>(hc, rel6, row_start, csr_src, csr_w,
                                            hidx, tdot, statsT, out_pred, l);
    } else {
      k_agg<false><<<NN/8, 256, 0, stream>>>(hc, rel6, row_start, csr_src, csr_w,
                                             hidx, tdot, statsT, out_pred, l);
    }
    k_lin<<<(NN+63)/64, 256, 0, stream>>>(hTc, statsT, lin_W, lin_b,
                                          scale_arr, inv_arr, hn, hTn, l);
    float* t1 = hc;  hc = hn;  hn = t1;
    float* t2 = hTc; hTc = hTn; hTn = t2;
  }
  k_mlp<<<nb, 256, 0, stream>>>(hTc, qc, W1, W2, b2, out_score);
}

// Round 3
// 785.828 us; speedup vs baseline: 1.4725x; 1.0478x over previous
//
#include <hip/hip_runtime.h>
#include <math.h>

#define NN 50000
#define EE 800000
#define DD 32

// deg packing: one double atomic per edge carries both count and sum(w):
//   pack += 65536.0 + w   ->  count = floor(pack/65536), sumw = pack - 65536*count
// Exact: sumw < 65536 strictly; double mantissa exact to ~1e-9 here.
__device__ __forceinline__ int pack_count(double p){ return (int)(p * (1.0/65536.0)); }
__device__ __forceinline__ float pack_sumw(double p){ return (float)(p - 65536.0 * (double)pack_count(p)); }

// ---------------- setup kernels ----------------

__global__ __launch_bounds__(256) void k_zero(float* p, int count){
  int i = blockIdx.x*256 + threadIdx.x;
  if (i < count) p[i] = 0.f;
}

__global__ __launch_bounds__(256) void k_hist(const int* __restrict__ node_out,
                                              const float* __restrict__ ew,
                                              double* __restrict__ deg_pack){
  int e = blockIdx.x*256 + threadIdx.x;
  if (e < EE){
    int o = node_out[e];
    atomicAdd(&deg_pack[o], 65536.0 + (double)ew[e]);
  }
}

__global__ __launch_bounds__(256) void k_logsum(const double* __restrict__ deg_pack,
                                                float* __restrict__ logsum){
  __shared__ float sd[256];
  int t = threadIdx.x; int n = blockIdx.x*256 + t;
  float v = 0.f;
  if (n < NN) v = logf(pack_sumw(deg_pack[n]) + 1.f);
  sd[t] = v; __syncthreads();
  for (int off = 128; off > 0; off >>= 1){
    if (t < off) sd[t] += sd[t+off];
    __syncthreads();
  }
  if (t == 0) atomicAdd(logsum, sd[0]);
}

__global__ __launch_bounds__(256) void k_scan1(const double* __restrict__ deg_pack,
                                               int* __restrict__ partials){
  __shared__ int sd[256];
  int t = threadIdx.x; int n = blockIdx.x*256 + t;
  sd[t] = (n < NN) ? pack_count(deg_pack[n]) : 0; __syncthreads();
  for (int off = 128; off > 0; off >>= 1){
    if (t < off) sd[t] += sd[t+off];
    __syncthreads();
  }
  if (t == 0) partials[blockIdx.x] = sd[0];
}

__global__ __launch_bounds__(256) void k_scan2(int* __restrict__ partials, int nb,
                                               int* __restrict__ row_start){
  __shared__ int sd[256];
  int t = threadIdx.x;
  int v = (t < nb) ? partials[t] : 0;
  sd[t] = v; __syncthreads();
  for (int off = 1; off < 256; off <<= 1){
    int x = (t >= off) ? sd[t-off] : 0;
    __syncthreads();
    sd[t] += x;
    __syncthreads();
  }
  if (t < nb) partials[t] = sd[t] - v;   // exclusive
  if (t == 0) row_start[NN] = EE;
}

__global__ __launch_bounds__(256) void k_scan3(const double* __restrict__ deg_pack,
                                               const int* __restrict__ partials,
                                               int* __restrict__ row_start,
                                               int* __restrict__ cursor){
  __shared__ int sd[256];
  int t = threadIdx.x; int n = blockIdx.x*256 + t;
  int v = (n < NN) ? pack_count(deg_pack[n]) : 0;
  sd[t] = v; __syncthreads();
  for (int off = 1; off < 256; off <<= 1){
    int x = (t >= off) ? sd[t-off] : 0;
    __syncthreads();
    sd[t] += x;
    __syncthreads();
  }
  if (n < NN){
    int rs = partials[blockIdx.x] + sd[t] - v;  // exclusive
    row_start[n] = rs; cursor[n] = rs;
  }
}

__global__ __launch_bounds__(256) void k_fillcsr(const int* __restrict__ node_in,
                                                 const int* __restrict__ node_out,
                                                 const float* __restrict__ ew,
                                                 int* __restrict__ cursor,
                                                 int2* __restrict__ csr){
  int e = blockIdx.x*256 + threadIdx.x;
  if (e < EE){
    int o = node_out[e];
    int pos = atomicAdd(&cursor[o], 1);
    int2 v; v.x = node_in[e]; v.y = __float_as_int(ew[e]);
    csr[pos] = v;
  }
}

__global__ __launch_bounds__(256) void k_scales(const double* __restrict__ deg_pack,
                                                const float* __restrict__ logsum,
                                                float* __restrict__ scale_arr,
                                                float* __restrict__ inv_arr){
  int n = blockIdx.x*256 + threadIdx.x;
  if (n < NN){
    float mean = *logsum / (float)NN;
    float s = logf(pack_sumw(deg_pack[n]) + 1.f) / mean;
    scale_arr[n] = s;
    inv_arr[n]   = 1.f / fmaxf(s, 0.01f);
  }
}

// rel_input per layer (6x32) and query-part of final MLP (64)
__global__ __launch_bounds__(256) void k_prep(const float* __restrict__ qw,
                                              const float* __restrict__ rel_W,
                                              const float* __restrict__ rel_b,
                                              const float* __restrict__ W1,
                                              const float* __restrict__ b1,
                                              float* __restrict__ rel6,
                                              float* __restrict__ qc){
  int t = threadIdx.x;
  if (t < 192){
    int l = t >> 5, j = t & 31;
    float s = rel_b[t];
    for (int d = 0; d < 32; ++d) s += qw[d] * rel_W[l*1024 + d*32 + j];
    rel6[t] = s;
  } else if (t < 256){
    int j = t - 192;
    float s = b1[j];
    for (int k = 0; k < 32; ++k) s += qw[k] * W1[(32+k)*64 + j];
    qc[j] = s;
  }
}

__global__ __launch_bounds__(256) void k_init_h(const int* __restrict__ hidx,
                                                float* __restrict__ h,
                                                float* __restrict__ hT){
  int i = blockIdx.x*256 + threadIdx.x;
  int hv = *hidx;
  if (i < NN*DD){
    h[i]  = ((i >> 5) == hv) ? 0.f : 100.f;   // row-major: n = i/32
    int n2 = i % NN;                           // transposed: n = i % N
    hT[i] = (n2 == hv) ? 0.f : 100.f;
  }
}

// t[n] = dot(h[n], rel_layer5) for msg_score  (keep same op order as reference
// tie semantics depend on bit-exact equality of w*tdot[src])
__global__ __launch_bounds__(256) void k_dot(const float* __restrict__ h,
                                             const float* __restrict__ rel6,
                                             float* __restrict__ tdot){
  int n0 = blockIdx.x*256 + threadIdx.x;
  int n = (n0 < NN) ? n0 : NN-1;
  const float* relr = rel6 + 5*32;
  float s = 0.f;
  #pragma unroll
  for (int d = 0; d < 32; ++d) s += h[n*32 + d] * relr[d];
  if (n0 < NN) tdot[n0] = s;
}

// ---------------- per-layer aggregation ----------------
// 32 lanes per node (lane = dim). Aggregates S1=sum(w*h), S2=sum(w*h^2),
// M=max(w*h), m=min(w*h) over in-edges; rel applied afterwards (h>=0, so
// max(rel*w*h) = rel>=0 ? rel*M : rel*m). Self-loop boundary row appended
// raw (no rel). Writes statsT[k'][n] (k' = d*4 + {mean,max,min,std}).
template<bool PRED>
__global__ __launch_bounds__(256) void k_agg(const float* __restrict__ h,
                                             const float* __restrict__ rel6,
                                             const int* __restrict__ row_start,
                                             const int2* __restrict__ csr,
                                             const int* __restrict__ hidx,
                                             const float* __restrict__ tdot,
                                             float* __restrict__ statsT,
                                             float* __restrict__ pred_out,
                                             int l){
  int tid = threadIdx.x;
  int g = tid >> 5, lane = tid & 31;
  int n = blockIdx.x*8 + g;              // 6250*8 == 50000 exactly
  int s0 = row_start[n], s1 = row_start[n+1];
  float S1 = 0.f, S2 = 0.f, M = -INFINITY, m = INFINITY;
  float best = -INFINITY; int bi = NN;
  for (int e = s0; e < s1; ++e){
    int2 ed = csr[e];
    int src  = ed.x;
    float w  = __int_as_float(ed.y);
    float hv = h[src*32 + lane];
    float wm = w * hv;
    S1 += wm; S2 += wm * hv;
    M = fmaxf(M, wm); m = fminf(m, wm);
    if (PRED){
      float scv = w * tdot[src];
      if (scv > best){ best = scv; bi = src; }
      else if (scv == best && src < bi) bi = src;
    }
  }
  int hv0 = *hidx;
  float bnd = (n == hv0) ? 0.f : 100.f;
  float rel = rel6[l*32 + lane];
  int deg = s1 - s0;
  float mx, mn;
  if (deg > 0){
    float em = (rel >= 0.f) ? rel*M : rel*m;
    float en = (rel >= 0.f) ? rel*m : rel*M;
    mx = fmaxf(em, bnd); mn = fminf(en, bnd);
  } else { mx = bnd; mn = bnd; }
  float cnt  = (float)(deg + 1);
  float mean = (rel*S1 + bnd) / cnt;
  float sq   = (rel*rel*S2 + bnd*bnd) / cnt;
  float sd   = sqrtf(fmaxf(sq - mean*mean, 1e-6f));

  if (PRED){
    float ss = (n == hv0) ? 0.f : 3200.f;   // sum of boundary row, w=1
    if (ss > best){ best = ss; bi = n; }
    else if (ss == best && n < bi) bi = n;
    if (lane == 0) pred_out[n] = (float)bi;
  }

  __shared__ float lds[8][129];
  lds[g][lane*4+0] = mean;
  lds[g][lane*4+1] = mx;
  lds[g][lane*4+2] = mn;
  lds[g][lane*4+3] = sd;
  __syncthreads();
  int nbase = blockIdx.x*8;
  for (int idx = tid; idx < 1024; idx += 256){
    int kp = idx >> 3, cc = idx & 7;
    statsT[kp*NN + nbase + cc] = lds[cc][kp];
  }
}

// ---------------- per-layer linear ----------------
// j-split: each wave computes 8 of 32 output dims for the block's 64 nodes,
// full K=416. j0 forced wave-scalar via readfirstlane so every W address is
// provably uniform -> s_load (scalar cache). No LDS, no cross-wave reduce.
__global__ __launch_bounds__(256) void k_lin(const float* __restrict__ hT,
                                             const float* __restrict__ statsT,
                                             const float* __restrict__ lin_W,
                                             const float* __restrict__ lin_b,
                                             const float* __restrict__ scale_arr,
                                             const float* __restrict__ inv_arr,
                                             float* __restrict__ h_next,
                                             float* __restrict__ hT_next,
                                             int l){
  const float* Wl = lin_W + (size_t)l * 13312;   // 416*32
  int tid = threadIdx.x;
  int lane = tid & 63;
  int j0 = __builtin_amdgcn_readfirstlane((tid >> 6) * 8);  // 0,8,16,24
  int n0 = blockIdx.x*64 + lane;
  int n = (n0 < NN) ? n0 : NN-1;
  float sc = scale_arr[n], iv = inv_arr[n];
  float acc[8];
  #pragma unroll
  for (int j = 0; j < 8; ++j) acc[j] = lin_b[l*32 + j0 + j];

  // h part: rows 0..32
  for (int k = 0; k < 32; ++k){
    float xv = hT[k*NN + n];
    const float* wr = Wl + k*32 + j0;
    #pragma unroll
    for (int j = 0; j < 8; ++j) acc[j] += xv * wr[j];
  }
  // stats part: kp = d*4 + c -> W rows 32 + d*12 + c*3 + {0,1,2}
  for (int kp = 0; kp < 128; ++kp){
    float f = statsT[kp*NN + n];
    int d = kp >> 2, c = kp & 3;
    const float* wr = Wl + (32 + d*12 + c*3)*32 + j0;
    float f1 = f*sc, f2 = f*iv;
    #pragma unroll
    for (int j = 0; j < 8; ++j)
      acc[j] += f*wr[j] + f1*wr[32+j] + f2*wr[64+j];
  }

  if (n0 < NN){
    #pragma unroll
    for (int j = 0; j < 8; ++j){
      float v = fmaxf(acc[j], 0.f);
      h_next[n0*32 + j0 + j] = v;
      hT_next[(j0+j)*NN + n0] = v;
    }
  }
}

// ---------------- final MLP ----------------
__global__ __launch_bounds__(256) void k_mlp(const float* __restrict__ hT,
                                             const float* __restrict__ qc,
                                             const float* __restrict__ W1,
                                             const float* __restrict__ W2,
                                             const float* __restrict__ b2,
                                             float* __restrict__ out_score){
  int n0 = blockIdx.x*256 + threadIdx.x;
  int n = (n0 < NN) ? n0 : NN-1;
  float acc[64];
  #pragma unroll
  for (int j = 0; j < 64; ++j) acc[j] = qc[j];
  for (int k = 0; k < 32; ++k){
    float xv = hT[k*NN + n];
    const float* wr = W1 + k*64;
    #pragma unroll
    for (int j = 0; j < 64; ++j) acc[j] += xv * wr[j];
  }
  float s = b2[0];
  #pragma unroll
  for (int j = 0; j < 64; ++j) s += fmaxf(acc[j], 0.f) * W2[j];
  if (n0 < NN) out_score[n0] = s;
}

// ---------------- host launch ----------------
extern "C" void kernel_launch(void* const* d_in, const int* in_sizes, int n_in,
                              void* d_out, int out_size, void* d_ws, size_t ws_size,
                              hipStream_t stream){
  const int*   node_in  = (const int*)d_in[0];
  const int*   node_out = (const int*)d_in[1];
  const float* ew       = (const float*)d_in[2];
  const int*   hidx     = (const int*)d_in[3];
  const float* qw       = (const float*)d_in[4];
  const float* rel_W    = (const float*)d_in[5];
  const float* rel_b    = (const float*)d_in[6];
  const float* lin_W    = (const float*)d_in[7];
  const float* lin_b    = (const float*)d_in[8];
  const float* W1       = (const float*)d_in[9];
  const float* b1       = (const float*)d_in[10];
  const float* W2       = (const float*)d_in[11];
  const float* b2       = (const float*)d_in[12];
  float* out_score = (float*)d_out;
  float* out_pred  = out_score + NN;

  char* w = (char*)d_ws;
  size_t off = 0;
  auto take = [&](size_t bytes)->char*{
    char* p = w + off;
    off = (off + bytes + 255) & ~(size_t)255;
    return p;
  };
  // contiguous zero block: deg_pack (N doubles) | logsum (64 f)
  double* deg_pack = (double*)take((size_t)NN*8 + 64*4);
  float*  logsum   = (float*)(deg_pack + NN);
  int*   row_start = (int*)take((size_t)(NN+1)*4);
  int*   cursor    = (int*)take((size_t)NN*4);
  int*   partials  = (int*)take(256*4);
  float* rel6      = (float*)take(192*4);
  float* qc        = (float*)take(64*4);
  float* scale_arr = (float*)take((size_t)NN*4);
  float* inv_arr   = (float*)take((size_t)NN*4);
  float* tdot      = (float*)take((size_t)NN*4);
  int2*  csr       = (int2*)take((size_t)EE*8);
  float* h_a       = (float*)take((size_t)NN*32*4);
  float* hT_a      = (float*)take((size_t)NN*32*4);
  float* h_b       = (float*)take((size_t)NN*32*4);
  float* hT_b      = (float*)take((size_t)NN*32*4);
  float* statsT    = (float*)take((size_t)NN*128*4);

  int zc = 2*NN + 64;   // N doubles == 2N floats, + logsum block
  int nb = (NN + 255) / 256;   // 196
  k_zero   <<<(zc+255)/256, 256, 0, stream>>>((float*)deg_pack, zc);
  k_hist   <<<(EE+255)/256, 256, 0, stream>>>(node_out, ew, deg_pack);
  k_logsum <<<nb, 256, 0, stream>>>(deg_pack, logsum);
  k_scan1  <<<nb, 256, 0, stream>>>(deg_pack, partials);
  k_scan2  <<<1, 256, 0, stream>>>(partials, nb, row_start);
  k_scan3  <<<nb, 256, 0, stream>>>(deg_pack, partials, row_start, cursor);
  k_fillcsr<<<(EE+255)/256, 256, 0, stream>>>(node_in, node_out, ew, cursor, csr);
  k_scales <<<nb, 256, 0, stream>>>(deg_pack, logsum, scale_arr, inv_arr);
  k_prep   <<<1, 256, 0, stream>>>(qw, rel_W, rel_b, W1, b1, rel6, qc);
  k_init_h <<<(NN*DD+255)/256, 256, 0, stream>>>(hidx, h_a, hT_a);

  float* hc = h_a;  float* hTc = hT_a;
  float* hn = h_b;  float* hTn = hT_b;
  for (int l = 0; l < 6; ++l){
    if (l == 5){
      k_dot<<<nb, 256, 0, stream>>>(hc, rel6, tdot);
      k_agg<true><<<NN/8, 256, 0, stream>>>(hc, rel6, row_start, csr,
                                            hidx, tdot, statsT, out_pred, l);
    } else {
      k_agg<false><<<NN/8, 256, 0, stream>>>(hc, rel6, row_start, csr,
                                             hidx, tdot, statsT, out_pred, l);
    }
    k_lin<<<(NN+63)/64, 256, 0, stream>>>(hTc, statsT, lin_W, lin_b,
                                          scale_arr, inv_arr, hn, hTn, l);
    float* t1 = hc;  hc = hn;  hn = t1;
    float* t2 = hTc; hTc = hTn; hTn = t2;
  }
  k_mlp<<<nb, 256, 0, stream>>>(hTc, qc, W1, W2, b2, out_score);
}

// Round 4
// 668.998 us; speedup vs baseline: 1.7296x; 1.1746x over previous
//
#include <hip/hip_runtime.h>
#include <math.h>

#define NN 50000
#define EE 800000
#define DD 32

// deg packing: one double atomic per edge carries both count and sum(w):
//   pack += 65536.0 + w   ->  count = floor(pack/65536), sumw = pack - 65536*count
__device__ __forceinline__ int pack_count(double p){ return (int)(p * (1.0/65536.0)); }
__device__ __forceinline__ float pack_sumw(double p){ return (float)(p - 65536.0 * (double)pack_count(p)); }

// ---------------- setup kernels ----------------

__global__ __launch_bounds__(256) void k_zero(float* p, int count){
  int i = blockIdx.x*256 + threadIdx.x;
  if (i < count) p[i] = 0.f;
}

__global__ __launch_bounds__(256) void k_hist(const int* __restrict__ node_out,
                                              const float* __restrict__ ew,
                                              double* __restrict__ deg_pack){
  int e = blockIdx.x*256 + threadIdx.x;
  if (e < EE){
    int o = node_out[e];
    atomicAdd(&deg_pack[o], 65536.0 + (double)ew[e]);
  }
}

__global__ __launch_bounds__(256) void k_logsum(const double* __restrict__ deg_pack,
                                                float* __restrict__ logsum){
  __shared__ float sd[256];
  int t = threadIdx.x; int n = blockIdx.x*256 + t;
  float v = 0.f;
  if (n < NN) v = logf(pack_sumw(deg_pack[n]) + 1.f);
  sd[t] = v; __syncthreads();
  for (int off = 128; off > 0; off >>= 1){
    if (t < off) sd[t] += sd[t+off];
    __syncthreads();
  }
  if (t == 0) atomicAdd(logsum, sd[0]);
}

__global__ __launch_bounds__(256) void k_scan1(const double* __restrict__ deg_pack,
                                               int* __restrict__ partials){
  __shared__ int sd[256];
  int t = threadIdx.x; int n = blockIdx.x*256 + t;
  sd[t] = (n < NN) ? pack_count(deg_pack[n]) : 0; __syncthreads();
  for (int off = 128; off > 0; off >>= 1){
    if (t < off) sd[t] += sd[t+off];
    __syncthreads();
  }
  if (t == 0) partials[blockIdx.x] = sd[0];
}

__global__ __launch_bounds__(256) void k_scan2(int* __restrict__ partials, int nb,
                                               int* __restrict__ row_start){
  __shared__ int sd[256];
  int t = threadIdx.x;
  int v = (t < nb) ? partials[t] : 0;
  sd[t] = v; __syncthreads();
  for (int off = 1; off < 256; off <<= 1){
    int x = (t >= off) ? sd[t-off] : 0;
    __syncthreads();
    sd[t] += x;
    __syncthreads();
  }
  if (t < nb) partials[t] = sd[t] - v;   // exclusive
  if (t == 0) row_start[NN] = EE;
}

__global__ __launch_bounds__(256) void k_scan3(const double* __restrict__ deg_pack,
                                               const int* __restrict__ partials,
                                               int* __restrict__ row_start,
                                               int* __restrict__ cursor){
  __shared__ int sd[256];
  int t = threadIdx.x; int n = blockIdx.x*256 + t;
  int v = (n < NN) ? pack_count(deg_pack[n]) : 0;
  sd[t] = v; __syncthreads();
  for (int off = 1; off < 256; off <<= 1){
    int x = (t >= off) ? sd[t-off] : 0;
    __syncthreads();
    sd[t] += x;
    __syncthreads();
  }
  if (n < NN){
    int rs = partials[blockIdx.x] + sd[t] - v;  // exclusive
    row_start[n] = rs; cursor[n] = rs;
  }
}

__global__ __launch_bounds__(256) void k_fillcsr(const int* __restrict__ node_in,
                                                 const int* __restrict__ node_out,
                                                 const float* __restrict__ ew,
                                                 int* __restrict__ cursor,
                                                 int2* __restrict__ csr){
  int e = blockIdx.x*256 + threadIdx.x;
  if (e < EE){
    int o = node_out[e];
    int pos = atomicAdd(&cursor[o], 1);
    int2 v; v.x = node_in[e]; v.y = __float_as_int(ew[e]);
    csr[pos] = v;
  }
}

__global__ __launch_bounds__(256) void k_scales(const double* __restrict__ deg_pack,
                                                const float* __restrict__ logsum,
                                                float* __restrict__ scale_arr,
                                                float* __restrict__ inv_arr){
  int n = blockIdx.x*256 + threadIdx.x;
  if (n < NN){
    float mean = *logsum / (float)NN;
    float s = logf(pack_sumw(deg_pack[n]) + 1.f) / mean;
    scale_arr[n] = s;
    inv_arr[n]   = 1.f / fmaxf(s, 0.01f);
  }
}

// rel_input per layer (6x32) and query-part of final MLP (64)
__global__ __launch_bounds__(256) void k_prep(const float* __restrict__ qw,
                                              const float* __restrict__ rel_W,
                                              const float* __restrict__ rel_b,
                                              const float* __restrict__ W1,
                                              const float* __restrict__ b1,
                                              float* __restrict__ rel6,
                                              float* __restrict__ qc){
  int t = threadIdx.x;
  if (t < 192){
    int l = t >> 5, j = t & 31;
    float s = rel_b[t];
    for (int d = 0; d < 32; ++d) s += qw[d] * rel_W[l*1024 + d*32 + j];
    rel6[t] = s;
  } else if (t < 256){
    int j = t - 192;
    float s = b1[j];
    for (int k = 0; k < 32; ++k) s += qw[k] * W1[(32+k)*64 + j];
    qc[j] = s;
  }
}

__global__ __launch_bounds__(256) void k_init_h(const int* __restrict__ hidx,
                                                float* __restrict__ h,
                                                float* __restrict__ hT){
  int i = blockIdx.x*256 + threadIdx.x;
  int hv = *hidx;
  if (i < NN*DD){
    h[i]  = ((i >> 5) == hv) ? 0.f : 100.f;   // row-major: n = i/32
    int n2 = i % NN;                           // transposed: n = i % N
    hT[i] = (n2 == hv) ? 0.f : 100.f;
  }
}

// t[n] = dot(h[n], rel_layer5) for msg_score
__global__ __launch_bounds__(256) void k_dot(const float* __restrict__ h,
                                             const float* __restrict__ rel6,
                                             float* __restrict__ tdot){
  int n0 = blockIdx.x*256 + threadIdx.x;
  int n = (n0 < NN) ? n0 : NN-1;
  const float* relr = rel6 + 5*32;
  float s = 0.f;
  #pragma unroll
  for (int d = 0; d < 32; ++d) s += h[n*32 + d] * relr[d];
  if (n0 < NN) tdot[n0] = s;
}

// ---------------- fused per-layer kernel ----------------
// Block = 64 nodes, 256 threads.
// Phase 1 (agg): 8 half-wave groups (32 lanes = dim), each handles 8 nodes.
//   Edge loop unrolled x4 -> 4 independent h-row gathers in flight.
//   Stats (mean,max,min,std per dim) -> LDS sh[64][129] (pad: conflict-free).
// Phase 2 (lin): proven j-split: wave w computes dims w*8..w*8+7 for the 64
//   nodes (node-per-lane); W addresses wave-uniform -> s_load. Stats from LDS.
template<bool PRED>
__global__ __launch_bounds__(256) void k_layer(const float* __restrict__ h,
                                               const float* __restrict__ hT,
                                               const float* __restrict__ rel6,
                                               const int* __restrict__ row_start,
                                               const int2* __restrict__ csr,
                                               const int* __restrict__ hidx,
                                               const float* __restrict__ tdot,
                                               const float* __restrict__ lin_W,
                                               const float* __restrict__ lin_b,
                                               const float* __restrict__ scale_arr,
                                               const float* __restrict__ inv_arr,
                                               float* __restrict__ h_next,
                                               float* __restrict__ hT_next,
                                               float* __restrict__ pred_out,
                                               int l){
  __shared__ float sh[64*129];
  int tid = threadIdx.x;
  int base = blockIdx.x * 64;
  int hv0 = *hidx;

  // ---- phase 1: aggregation ----
  {
    int g = tid >> 5, lane = tid & 31;
    float rel = rel6[l*32 + lane];
    for (int i = 0; i < 8; ++i){
      int nl = g*8 + i;
      int n  = base + nl;
      if (n >= NN) break;
      int s0 = row_start[n], s1 = row_start[n+1];
      float S1 = 0.f, S2 = 0.f, M = -INFINITY, m = INFINITY;
      float best = -INFINITY; int bi = NN;
      int e = s0;
      for (; e + 4 <= s1; e += 4){
        int2 d0 = csr[e+0], d1 = csr[e+1], d2 = csr[e+2], d3 = csr[e+3];
        float h0 = h[d0.x*32 + lane];
        float h1 = h[d1.x*32 + lane];
        float h2 = h[d2.x*32 + lane];
        float h3 = h[d3.x*32 + lane];
        float t0=0.f, t1=0.f, t2=0.f, t3=0.f;
        if (PRED){ t0 = tdot[d0.x]; t1 = tdot[d1.x]; t2 = tdot[d2.x]; t3 = tdot[d3.x]; }
        float w0 = __int_as_float(d0.y), w1 = __int_as_float(d1.y);
        float w2 = __int_as_float(d2.y), w3 = __int_as_float(d3.y);
        // sequential order preserved (bit-identical accumulation)
        float wm;
        wm = w0*h0; S1 += wm; S2 += wm*h0; M = fmaxf(M,wm); m = fminf(m,wm);
        if (PRED){ float sv = w0*t0; if (sv > best){best=sv; bi=d0.x;} else if (sv==best && d0.x<bi) bi=d0.x; }
        wm = w1*h1; S1 += wm; S2 += wm*h1; M = fmaxf(M,wm); m = fminf(m,wm);
        if (PRED){ float sv = w1*t1; if (sv > best){best=sv; bi=d1.x;} else if (sv==best && d1.x<bi) bi=d1.x; }
        wm = w2*h2; S1 += wm; S2 += wm*h2; M = fmaxf(M,wm); m = fminf(m,wm);
        if (PRED){ float sv = w2*t2; if (sv > best){best=sv; bi=d2.x;} else if (sv==best && d2.x<bi) bi=d2.x; }
        wm = w3*h3; S1 += wm; S2 += wm*h3; M = fmaxf(M,wm); m = fminf(m,wm);
        if (PRED){ float sv = w3*t3; if (sv > best){best=sv; bi=d3.x;} else if (sv==best && d3.x<bi) bi=d3.x; }
      }
      for (; e < s1; ++e){
        int2 ed = csr[e];
        int src = ed.x;
        float w = __int_as_float(ed.y);
        float hvv = h[src*32 + lane];
        float wm = w * hvv;
        S1 += wm; S2 += wm*hvv; M = fmaxf(M,wm); m = fminf(m,wm);
        if (PRED){
          float sv = w * tdot[src];
          if (sv > best){ best = sv; bi = src; }
          else if (sv == best && src < bi) bi = src;
        }
      }
      float bnd = (n == hv0) ? 0.f : 100.f;
      int deg = s1 - s0;
      float mx, mn;
      if (deg > 0){
        float em = (rel >= 0.f) ? rel*M : rel*m;
        float en = (rel >= 0.f) ? rel*m : rel*M;
        mx = fmaxf(em, bnd); mn = fminf(en, bnd);
      } else { mx = bnd; mn = bnd; }
      float cnt  = (float)(deg + 1);
      float mean = (rel*S1 + bnd) / cnt;
      float sq   = (rel*rel*S2 + bnd*bnd) / cnt;
      float sd   = sqrtf(fmaxf(sq - mean*mean, 1e-6f));

      if (PRED){
        float ss = (n == hv0) ? 0.f : 3200.f;   // boundary self-loop row sum, w=1
        if (ss > best){ best = ss; bi = n; }
        else if (ss == best && n < bi) bi = n;
        if (lane == 0) pred_out[n] = (float)bi;
      }

      float* row = sh + nl*129 + lane*4;
      row[0] = mean; row[1] = mx; row[2] = mn; row[3] = sd;
    }
  }
  __syncthreads();

  // ---- phase 2: linear ----
  {
    const float* Wl = lin_W + (size_t)l * 13312;   // 416*32
    int lane = tid & 63;
    int j0 = __builtin_amdgcn_readfirstlane((tid >> 6) * 8);  // 0,8,16,24
    int n0 = base + lane;
    int n = (n0 < NN) ? n0 : NN-1;
    float sc = scale_arr[n], iv = inv_arr[n];
    float acc[8];
    #pragma unroll
    for (int j = 0; j < 8; ++j) acc[j] = lin_b[l*32 + j0 + j];

    for (int k = 0; k < 32; ++k){
      float xv = hT[k*NN + n];
      const float* wr = Wl + k*32 + j0;
      #pragma unroll
      for (int j = 0; j < 8; ++j) acc[j] += xv * wr[j];
    }
    const float* srow = sh + lane*129;
    for (int kp = 0; kp < 128; ++kp){
      float f = srow[kp];
      int d = kp >> 2, c = kp & 3;
      const float* wr = Wl + (32 + d*12 + c*3)*32 + j0;
      float f1 = f*sc, f2 = f*iv;
      #pragma unroll
      for (int j = 0; j < 8; ++j)
        acc[j] += f*wr[j] + f1*wr[32+j] + f2*wr[64+j];
    }

    if (n0 < NN){
      #pragma unroll
      for (int j = 0; j < 8; ++j){
        float v = fmaxf(acc[j], 0.f);
        h_next[n0*32 + j0 + j] = v;
        hT_next[(j0+j)*NN + n0] = v;
      }
    }
  }
}

// ---------------- final MLP ----------------
__global__ __launch_bounds__(256) void k_mlp(const float* __restrict__ hT,
                                             const float* __restrict__ qc,
                                             const float* __restrict__ W1,
                                             const float* __restrict__ W2,
                                             const float* __restrict__ b2,
                                             float* __restrict__ out_score){
  int n0 = blockIdx.x*256 + threadIdx.x;
  int n = (n0 < NN) ? n0 : NN-1;
  float acc[64];
  #pragma unroll
  for (int j = 0; j < 64; ++j) acc[j] = qc[j];
  for (int k = 0; k < 32; ++k){
    float xv = hT[k*NN + n];
    const float* wr = W1 + k*64;
    #pragma unroll
    for (int j = 0; j < 64; ++j) acc[j] += xv * wr[j];
  }
  float s = b2[0];
  #pragma unroll
  for (int j = 0; j < 64; ++j) s += fmaxf(acc[j], 0.f) * W2[j];
  if (n0 < NN) out_score[n0] = s;
}

// ---------------- host launch ----------------
extern "C" void kernel_launch(void* const* d_in, const int* in_sizes, int n_in,
                              void* d_out, int out_size, void* d_ws, size_t ws_size,
                              hipStream_t stream){
  const int*   node_in  = (const int*)d_in[0];
  const int*   node_out = (const int*)d_in[1];
  const float* ew       = (const float*)d_in[2];
  const int*   hidx     = (const int*)d_in[3];
  const float* qw       = (const float*)d_in[4];
  const float* rel_W    = (const float*)d_in[5];
  const float* rel_b    = (const float*)d_in[6];
  const float* lin_W    = (const float*)d_in[7];
  const float* lin_b    = (const float*)d_in[8];
  const float* W1       = (const float*)d_in[9];
  const float* b1       = (const float*)d_in[10];
  const float* W2       = (const float*)d_in[11];
  const float* b2       = (const float*)d_in[12];
  float* out_score = (float*)d_out;
  float* out_pred  = out_score + NN;

  char* w = (char*)d_ws;
  size_t off = 0;
  auto take = [&](size_t bytes)->char*{
    char* p = w + off;
    off = (off + bytes + 255) & ~(size_t)255;
    return p;
  };
  double* deg_pack = (double*)take((size_t)NN*8 + 64*4);
  float*  logsum   = (float*)(deg_pack + NN);
  int*   row_start = (int*)take((size_t)(NN+1)*4);
  int*   cursor    = (int*)take((size_t)NN*4);
  int*   partials  = (int*)take(256*4);
  float* rel6      = (float*)take(192*4);
  float* qc        = (float*)take(64*4);
  float* scale_arr = (float*)take((size_t)NN*4);
  float* inv_arr   = (float*)take((size_t)NN*4);
  float* tdot      = (float*)take((size_t)NN*4);
  int2*  csr       = (int2*)take((size_t)EE*8);
  float* h_a       = (float*)take((size_t)NN*32*4);
  float* hT_a      = (float*)take((size_t)NN*32*4);
  float* h_b       = (float*)take((size_t)NN*32*4);
  float* hT_b      = (float*)take((size_t)NN*32*4);

  int zc = 2*NN + 64;   // N doubles == 2N floats, + logsum block
  int nb = (NN + 255) / 256;   // 196
  int nlb = (NN + 63) / 64;    // 782
  k_zero   <<<(zc+255)/256, 256, 0, stream>>>((float*)deg_pack, zc);
  k_hist   <<<(EE+255)/256, 256, 0, stream>>>(node_out, ew, deg_pack);
  k_logsum <<<nb, 256, 0, stream>>>(deg_pack, logsum);
  k_scan1  <<<nb, 256, 0, stream>>>(deg_pack, partials);
  k_scan2  <<<1, 256, 0, stream>>>(partials, nb, row_start);
  k_scan3  <<<nb, 256, 0, stream>>>(deg_pack, partials, row_start, cursor);
  k_fillcsr<<<(EE+255)/256, 256, 0, stream>>>(node_in, node_out, ew, cursor, csr);
  k_scales <<<nb, 256, 0, stream>>>(deg_pack, logsum, scale_arr, inv_arr);
  k_prep   <<<1, 256, 0, stream>>>(qw, rel_W, rel_b, W1, b1, rel6, qc);
  k_init_h <<<(NN*DD+255)/256, 256, 0, stream>>>(hidx, h_a, hT_a);

  float* hc = h_a;  float* hTc = hT_a;
  float* hn = h_b;  float* hTn = hT_b;
  for (int l = 0; l < 6; ++l){
    if (l == 5){
      k_dot<<<nb, 256, 0, stream>>>(hc, rel6, tdot);
      k_layer<true><<<nlb, 256, 0, stream>>>(hc, hTc, rel6, row_start, csr,
                                             hidx, tdot, lin_W, lin_b,
                                             scale_arr, inv_arr, hn, hTn,
                                             out_pred, l);
    } else {
      k_layer<false><<<nlb, 256, 0, stream>>>(hc, hTc, rel6, row_start, csr,
                                              hidx, tdot, lin_W, lin_b,
                                              scale_arr, inv_arr, hn, hTn,
                                              out_pred, l);
    }
    float* t1 = hc;  hc = hn;  hn = t1;
    float* t2 = hTc; hTc = hTn; hTn = t2;
  }
  k_mlp<<<nb, 256, 0, stream>>>(hTc, qc, W1, W2, b2, out_score);
}

// Round 5
// 635.937 us; speedup vs baseline: 1.8196x; 1.0520x over previous
//
#include <hip/hip_runtime.h>
#include <math.h>

#define NN 50000
#define EE 800000
#define DD 32

// deg packing: one double atomic per edge carries both count and sum(w):
//   pack += 65536.0 + w   ->  count = floor(pack/65536), sumw = pack - 65536*count
__device__ __forceinline__ int pack_count(double p){ return (int)(p * (1.0/65536.0)); }
__device__ __forceinline__ float pack_sumw(double p){ return (float)(p - 65536.0 * (double)pack_count(p)); }

// ---------------- setup kernels ----------------

__global__ __launch_bounds__(256) void k_zero(float* p, int count){
  int i = blockIdx.x*256 + threadIdx.x;
  if (i < count) p[i] = 0.f;
}

__global__ __launch_bounds__(256) void k_hist(const int* __restrict__ node_out,
                                              const float* __restrict__ ew,
                                              double* __restrict__ deg_pack){
  int e = blockIdx.x*256 + threadIdx.x;
  if (e < EE){
    int o = node_out[e];
    atomicAdd(&deg_pack[o], 65536.0 + (double)ew[e]);
  }
}

__global__ __launch_bounds__(256) void k_logsum(const double* __restrict__ deg_pack,
                                                float* __restrict__ logsum){
  __shared__ float sd[256];
  int t = threadIdx.x; int n = blockIdx.x*256 + t;
  float v = 0.f;
  if (n < NN) v = logf(pack_sumw(deg_pack[n]) + 1.f);
  sd[t] = v; __syncthreads();
  for (int off = 128; off > 0; off >>= 1){
    if (t < off) sd[t] += sd[t+off];
    __syncthreads();
  }
  if (t == 0) atomicAdd(logsum, sd[0]);
}

__global__ __launch_bounds__(256) void k_scan1(const double* __restrict__ deg_pack,
                                               int* __restrict__ partials){
  __shared__ int sd[256];
  int t = threadIdx.x; int n = blockIdx.x*256 + t;
  sd[t] = (n < NN) ? pack_count(deg_pack[n]) : 0; __syncthreads();
  for (int off = 128; off > 0; off >>= 1){
    if (t < off) sd[t] += sd[t+off];
    __syncthreads();
  }
  if (t == 0) partials[blockIdx.x] = sd[0];
}

__global__ __launch_bounds__(256) void k_scan2(int* __restrict__ partials, int nb,
                                               int* __restrict__ row_start){
  __shared__ int sd[256];
  int t = threadIdx.x;
  int v = (t < nb) ? partials[t] : 0;
  sd[t] = v; __syncthreads();
  for (int off = 1; off < 256; off <<= 1){
    int x = (t >= off) ? sd[t-off] : 0;
    __syncthreads();
    sd[t] += x;
    __syncthreads();
  }
  if (t < nb) partials[t] = sd[t] - v;   // exclusive
  if (t == 0) row_start[NN] = EE;
}

__global__ __launch_bounds__(256) void k_scan3(const double* __restrict__ deg_pack,
                                               const int* __restrict__ partials,
                                               int* __restrict__ row_start,
                                               int* __restrict__ cursor){
  __shared__ int sd[256];
  int t = threadIdx.x; int n = blockIdx.x*256 + t;
  int v = (n < NN) ? pack_count(deg_pack[n]) : 0;
  sd[t] = v; __syncthreads();
  for (int off = 1; off < 256; off <<= 1){
    int x = (t >= off) ? sd[t-off] : 0;
    __syncthreads();
    sd[t] += x;
    __syncthreads();
  }
  if (n < NN){
    int rs = partials[blockIdx.x] + sd[t] - v;  // exclusive
    row_start[n] = rs; cursor[n] = rs;
  }
}

__global__ __launch_bounds__(256) void k_fillcsr(const int* __restrict__ node_in,
                                                 const int* __restrict__ node_out,
                                                 const float* __restrict__ ew,
                                                 int* __restrict__ cursor,
                                                 int2* __restrict__ csr){
  int e = blockIdx.x*256 + threadIdx.x;
  if (e < EE){
    int o = node_out[e];
    int pos = atomicAdd(&cursor[o], 1);
    int2 v; v.x = node_in[e]; v.y = __float_as_int(ew[e]);
    csr[pos] = v;
  }
}

__global__ __launch_bounds__(256) void k_scales(const double* __restrict__ deg_pack,
                                                const float* __restrict__ logsum,
                                                float* __restrict__ scale_arr,
                                                float* __restrict__ inv_arr){
  int n = blockIdx.x*256 + threadIdx.x;
  if (n < NN){
    float mean = *logsum / (float)NN;
    float s = logf(pack_sumw(deg_pack[n]) + 1.f) / mean;
    scale_arr[n] = s;
    inv_arr[n]   = 1.f / fmaxf(s, 0.01f);
  }
}

// rel_input per layer (6x32) and query-part of final MLP (64)
__global__ __launch_bounds__(256) void k_prep(const float* __restrict__ qw,
                                              const float* __restrict__ rel_W,
                                              const float* __restrict__ rel_b,
                                              const float* __restrict__ W1,
                                              const float* __restrict__ b1,
                                              float* __restrict__ rel6,
                                              float* __restrict__ qc){
  int t = threadIdx.x;
  if (t < 192){
    int l = t >> 5, j = t & 31;
    float s = rel_b[t];
    for (int d = 0; d < 32; ++d) s += qw[d] * rel_W[l*1024 + d*32 + j];
    rel6[t] = s;
  } else if (t < 256){
    int j = t - 192;
    float s = b1[j];
    for (int k = 0; k < 32; ++k) s += qw[k] * W1[(32+k)*64 + j];
    qc[j] = s;
  }
}

__global__ __launch_bounds__(256) void k_init_h(const int* __restrict__ hidx,
                                                float* __restrict__ h,
                                                float* __restrict__ hT){
  int i = blockIdx.x*256 + threadIdx.x;
  int hv = *hidx;
  if (i < NN*DD){
    h[i]  = ((i >> 5) == hv) ? 0.f : 100.f;   // row-major: n = i/32
    int n2 = i % NN;                           // transposed: n = i % N
    hT[i] = (n2 == hv) ? 0.f : 100.f;
  }
}

// t[n] = dot(h[n], rel_layer5) for msg_score
__global__ __launch_bounds__(256) void k_dot(const float* __restrict__ h,
                                             const float* __restrict__ rel6,
                                             float* __restrict__ tdot){
  int n0 = blockIdx.x*256 + threadIdx.x;
  int n = (n0 < NN) ? n0 : NN-1;
  const float* relr = rel6 + 5*32;
  float s = 0.f;
  #pragma unroll
  for (int d = 0; d < 32; ++d) s += h[n*32 + d] * relr[d];
  if (n0 < NN) tdot[n0] = s;
}

// ---------------- fused per-layer kernel ----------------
// Block = 64 nodes, 256 threads. LDS = [128 stats][64 nodes] XOR-swizzled
// (32768 B exactly -> 5 blocks/CU ceiling; conflict-free phase-2 reads).
// Phase 1: 8 half-wave groups (32 lanes = dim); each group owns 8 consecutive
//   nodes = one CONTIGUOUS CSR range, processed as a continuous stream of
//   8-edge batches with csr prefetched one batch ahead (8 gathers + 8 csr
//   loads in flight). Node boundaries via shift-register walk; accumulation
//   order per node is preserved (bit-identical vs unfused).
// Phase 2: j-split linear (wave-uniform W addresses -> s_load).
template<bool PRED>
__global__ __launch_bounds__(256) void k_layer(const float* __restrict__ h,
                                               const float* __restrict__ hT,
                                               const float* __restrict__ rel6,
                                               const int* __restrict__ row_start,
                                               const int2* __restrict__ csr,
                                               const int* __restrict__ hidx,
                                               const float* __restrict__ tdot,
                                               const float* __restrict__ lin_W,
                                               const float* __restrict__ lin_b,
                                               const float* __restrict__ scale_arr,
                                               const float* __restrict__ inv_arr,
                                               float* __restrict__ h_next,
                                               float* __restrict__ hT_next,
                                               float* __restrict__ pred_out,
                                               int l){
  __shared__ float sh[128*64];
  int tid = threadIdx.x;
  int base = blockIdx.x * 64;
  int hv0 = *hidx;

  // ---- phase 1: aggregation ----
  {
    int g = tid >> 5, lane = tid & 31;
    int ng0 = base + g*8;
    int nend = ((ng0 + 8 <= NN) ? 8 : (NN - ng0));   // nodes in this group
    if (nend > 0){
      float rel = rel6[l*32 + lane];
      auto rsv = [&](int i){ int idx = ng0 + i; return row_start[idx > NN ? NN : idx]; };
      int eBeg = rsv(0), eEnd = rsv(nend);
      // per-node end boundaries (shift-register)
      int node_end = rsv(1);
      int nb1 = rsv(2), nb2 = rsv(3), nb3 = rsv(4), nb4 = rsv(5),
          nb5 = rsv(6), nb6 = rsv(7), nb7 = rsv(8);

      int curn = ng0;
      float S1 = 0.f, S2 = 0.f, M = -INFINITY, m = INFINITY;
      float best = -INFINITY; int bi = NN;
      int dcnt = 0;

#define FINALIZE() do { \
      float bnd = (curn == hv0) ? 0.f : 100.f; \
      float mx, mn; \
      if (dcnt > 0){ \
        float em = (rel >= 0.f) ? rel*M : rel*m; \
        float en = (rel >= 0.f) ? rel*m : rel*M; \
        mx = fmaxf(em, bnd); mn = fminf(en, bnd); \
      } else { mx = bnd; mn = bnd; } \
      float cntf = (float)(dcnt + 1); \
      float mean = (rel*S1 + bnd) / cntf; \
      float sq   = (rel*rel*S2 + bnd*bnd) / cntf; \
      float sdv  = sqrtf(fmaxf(sq - mean*mean, 1e-6f)); \
      int nl = curn - base; \
      int kp0 = lane*4; \
      sh[(kp0+0)*64 + (nl ^ ( kp0   &31))] = mean; \
      sh[(kp0+1)*64 + (nl ^ ((kp0+1)&31))] = mx; \
      sh[(kp0+2)*64 + (nl ^ ((kp0+2)&31))] = mn; \
      sh[(kp0+3)*64 + (nl ^ ((kp0+3)&31))] = sdv; \
      if (PRED){ \
        float ss = (curn == hv0) ? 0.f : 3200.f; \
        if (ss > best){ best = ss; bi = curn; } \
        else if (ss == best && curn < bi) bi = curn; \
        if (lane == 0) pred_out[curn] = (float)bi; \
      } \
      S1 = 0.f; S2 = 0.f; M = -INFINITY; m = INFINITY; \
      best = -INFINITY; bi = NN; dcnt = 0; \
      ++curn; \
      node_end = nb1; nb1 = nb2; nb2 = nb3; nb3 = nb4; \
      nb4 = nb5; nb5 = nb6; nb6 = nb7; \
    } while(0)

      int2 c0,c1,c2,c3,c4,c5,c6,c7;
      {
        int e = eBeg;
        c0 = (e+0 < eEnd) ? csr[e+0] : make_int2(0,0);
        c1 = (e+1 < eEnd) ? csr[e+1] : make_int2(0,0);
        c2 = (e+2 < eEnd) ? csr[e+2] : make_int2(0,0);
        c3 = (e+3 < eEnd) ? csr[e+3] : make_int2(0,0);
        c4 = (e+4 < eEnd) ? csr[e+4] : make_int2(0,0);
        c5 = (e+5 < eEnd) ? csr[e+5] : make_int2(0,0);
        c6 = (e+6 < eEnd) ? csr[e+6] : make_int2(0,0);
        c7 = (e+7 < eEnd) ? csr[e+7] : make_int2(0,0);
      }
      for (int e = eBeg; e < eEnd; e += 8){
        // gathers for current batch (8 independent, in flight together)
        float h0 = h[c0.x*32 + lane], h1 = h[c1.x*32 + lane];
        float h2 = h[c2.x*32 + lane], h3 = h[c3.x*32 + lane];
        float h4 = h[c4.x*32 + lane], h5 = h[c5.x*32 + lane];
        float h6 = h[c6.x*32 + lane], h7 = h[c7.x*32 + lane];
        float t0=0,t1=0,t2=0,t3=0,t4=0,t5=0,t6=0,t7=0;
        if (PRED){
          t0 = tdot[c0.x]; t1 = tdot[c1.x]; t2 = tdot[c2.x]; t3 = tdot[c3.x];
          t4 = tdot[c4.x]; t5 = tdot[c5.x]; t6 = tdot[c6.x]; t7 = tdot[c7.x];
        }
        // prefetch next batch's csr
        int2 p0,p1,p2,p3,p4,p5,p6,p7;
        {
          int en = e + 8;
          p0 = (en+0 < eEnd) ? csr[en+0] : make_int2(0,0);
          p1 = (en+1 < eEnd) ? csr[en+1] : make_int2(0,0);
          p2 = (en+2 < eEnd) ? csr[en+2] : make_int2(0,0);
          p3 = (en+3 < eEnd) ? csr[en+3] : make_int2(0,0);
          p4 = (en+4 < eEnd) ? csr[en+4] : make_int2(0,0);
          p5 = (en+5 < eEnd) ? csr[en+5] : make_int2(0,0);
          p6 = (en+6 < eEnd) ? csr[en+6] : make_int2(0,0);
          p7 = (en+7 < eEnd) ? csr[en+7] : make_int2(0,0);
        }
        // accumulate (sequential order preserved; boundary walk between edges)
#define ACC(J, CJ, HJ, TJ) do { \
        int ee = e + J; \
        if (ee < eEnd){ \
          while (ee >= node_end) FINALIZE(); \
          float w = __int_as_float(CJ.y); \
          float wm = w * HJ; \
          S1 += wm; S2 += wm * HJ; \
          M = fmaxf(M, wm); m = fminf(m, wm); \
          ++dcnt; \
          if (PRED){ \
            float sv = w * TJ; \
            if (sv > best){ best = sv; bi = CJ.x; } \
            else if (sv == best && CJ.x < bi) bi = CJ.x; \
          } \
        } } while(0)
        ACC(0, c0, h0, t0); ACC(1, c1, h1, t1);
        ACC(2, c2, h2, t2); ACC(3, c3, h3, t3);
        ACC(4, c4, h4, t4); ACC(5, c5, h5, t5);
        ACC(6, c6, h6, t6); ACC(7, c7, h7, t7);
#undef ACC
        c0=p0; c1=p1; c2=p2; c3=p3; c4=p4; c5=p5; c6=p6; c7=p7;
      }
      // trailing finalizes (incl. empty nodes)
      while (curn < ng0 + nend) FINALIZE();
#undef FINALIZE
    }
  }
  __syncthreads();

  // ---- phase 2: linear ----
  {
    const float* Wl = lin_W + (size_t)l * 13312;   // 416*32
    int lane = tid & 63;
    int j0 = __builtin_amdgcn_readfirstlane((tid >> 6) * 8);  // 0,8,16,24
    int n0 = base + lane;
    int n = (n0 < NN) ? n0 : NN-1;
    float sc = scale_arr[n], iv = inv_arr[n];
    float acc[8];
    #pragma unroll
    for (int j = 0; j < 8; ++j) acc[j] = lin_b[l*32 + j0 + j];

    for (int k = 0; k < 32; ++k){
      float xv = hT[k*NN + n];
      const float* wr = Wl + k*32 + j0;
      #pragma unroll
      for (int j = 0; j < 8; ++j) acc[j] += xv * wr[j];
    }
    for (int kp = 0; kp < 128; ++kp){
      float f = sh[kp*64 + (lane ^ (kp & 31))];
      int d = kp >> 2, c = kp & 3;
      const float* wr = Wl + (32 + d*12 + c*3)*32 + j0;
      float f1 = f*sc, f2 = f*iv;
      #pragma unroll
      for (int j = 0; j < 8; ++j)
        acc[j] += f*wr[j] + f1*wr[32+j] + f2*wr[64+j];
    }

    if (n0 < NN){
      #pragma unroll
      for (int j = 0; j < 8; ++j){
        float v = fmaxf(acc[j], 0.f);
        h_next[n0*32 + j0 + j] = v;
        hT_next[(j0+j)*NN + n0] = v;
      }
    }
  }
}

// ---------------- final MLP ----------------
__global__ __launch_bounds__(256) void k_mlp(const float* __restrict__ hT,
                                             const float* __restrict__ qc,
                                             const float* __restrict__ W1,
                                             const float* __restrict__ W2,
                                             const float* __restrict__ b2,
                                             float* __restrict__ out_score){
  int n0 = blockIdx.x*256 + threadIdx.x;
  int n = (n0 < NN) ? n0 : NN-1;
  float acc[64];
  #pragma unroll
  for (int j = 0; j < 64; ++j) acc[j] = qc[j];
  for (int k = 0; k < 32; ++k){
    float xv = hT[k*NN + n];
    const float* wr = W1 + k*64;
    #pragma unroll
    for (int j = 0; j < 64; ++j) acc[j] += xv * wr[j];
  }
  float s = b2[0];
  #pragma unroll
  for (int j = 0; j < 64; ++j) s += fmaxf(acc[j], 0.f) * W2[j];
  if (n0 < NN) out_score[n0] = s;
}

// ---------------- host launch ----------------
extern "C" void kernel_launch(void* const* d_in, const int* in_sizes, int n_in,
                              void* d_out, int out_size, void* d_ws, size_t ws_size,
                              hipStream_t stream){
  const int*   node_in  = (const int*)d_in[0];
  const int*   node_out = (const int*)d_in[1];
  const float* ew       = (const float*)d_in[2];
  const int*   hidx     = (const int*)d_in[3];
  const float* qw       = (const float*)d_in[4];
  const float* rel_W    = (const float*)d_in[5];
  const float* rel_b    = (const float*)d_in[6];
  const float* lin_W    = (const float*)d_in[7];
  const float* lin_b    = (const float*)d_in[8];
  const float* W1       = (const float*)d_in[9];
  const float* b1       = (const float*)d_in[10];
  const float* W2       = (const float*)d_in[11];
  const float* b2       = (const float*)d_in[12];
  float* out_score = (float*)d_out;
  float* out_pred  = out_score + NN;

  char* w = (char*)d_ws;
  size_t off = 0;
  auto take = [&](size_t bytes)->char*{
    char* p = w + off;
    off = (off + bytes + 255) & ~(size_t)255;
    return p;
  };
  double* deg_pack = (double*)take((size_t)NN*8 + 64*4);
  float*  logsum   = (float*)(deg_pack + NN);
  int*   row_start = (int*)take((size_t)(NN+1)*4);
  int*   cursor    = (int*)take((size_t)NN*4);
  int*   partials  = (int*)take(256*4);
  float* rel6      = (float*)take(192*4);
  float* qc        = (float*)take(64*4);
  float* scale_arr = (float*)take((size_t)NN*4);
  float* inv_arr   = (float*)take((size_t)NN*4);
  float* tdot      = (float*)take((size_t)NN*4);
  int2*  csr       = (int2*)take((size_t)EE*8);
  float* h_a       = (float*)take((size_t)NN*32*4);
  float* hT_a      = (float*)take((size_t)NN*32*4);
  float* h_b       = (float*)take((size_t)NN*32*4);
  float* hT_b      = (float*)take((size_t)NN*32*4);

  int zc = 2*NN + 64;   // N doubles == 2N floats, + logsum block
  int nb = (NN + 255) / 256;   // 196
  int nlb = (NN + 63) / 64;    // 782
  k_zero   <<<(zc+255)/256, 256, 0, stream>>>((float*)deg_pack, zc);
  k_hist   <<<(EE+255)/256, 256, 0, stream>>>(node_out, ew, deg_pack);
  k_logsum <<<nb, 256, 0, stream>>>(deg_pack, logsum);
  k_scan1  <<<nb, 256, 0, stream>>>(deg_pack, partials);
  k_scan2  <<<1, 256, 0, stream>>>(partials, nb, row_start);
  k_scan3  <<<nb, 256, 0, stream>>>(deg_pack, partials, row_start, cursor);
  k_fillcsr<<<(EE+255)/256, 256, 0, stream>>>(node_in, node_out, ew, cursor, csr);
  k_scales <<<nb, 256, 0, stream>>>(deg_pack, logsum, scale_arr, inv_arr);
  k_prep   <<<1, 256, 0, stream>>>(qw, rel_W, rel_b, W1, b1, rel6, qc);
  k_init_h <<<(NN*DD+255)/256, 256, 0, stream>>>(hidx, h_a, hT_a);

  float* hc = h_a;  float* hTc = hT_a;
  float* hn = h_b;  float* hTn = hT_b;
  for (int l = 0; l < 6; ++l){
    if (l == 5){
      k_dot<<<nb, 256, 0, stream>>>(hc, rel6, tdot);
      k_layer<true><<<nlb, 256, 0, stream>>>(hc, hTc, rel6, row_start, csr,
                                             hidx, tdot, lin_W, lin_b,
                                             scale_arr, inv_arr, hn, hTn,
                                             out_pred, l);
    } else {
      k_layer<false><<<nlb, 256, 0, stream>>>(hc, hTc, rel6, row_start, csr,
                                              hidx, tdot, lin_W, lin_b,
                                              scale_arr, inv_arr, hn, hTn,
                                              out_pred, l);
    }
    float* t1 = hc;  hc = hn;  hn = t1;
    float* t2 = hTc; hTc = hTn; hTn = t2;
  }
  k_mlp<<<nb, 256, 0, stream>>>(hTc, qc, W1, W2, b2, out_score);
}

// Round 6
// 615.184 us; speedup vs baseline: 1.8809x; 1.0337x over previous
//
#include <hip/hip_runtime.h>
#include <math.h>

#define NN 50000
#define EE 800000
#define DD 32

// deg packing: one double atomic per edge carries both count and sum(w):
//   pack += 65536.0 + w   ->  count = floor(pack/65536), sumw = pack - 65536*count
__device__ __forceinline__ int pack_count(double p){ return (int)(p * (1.0/65536.0)); }
__device__ __forceinline__ float pack_sumw(double p){ return (float)(p - 65536.0 * (double)pack_count(p)); }

// ---------------- setup kernels ----------------

__global__ __launch_bounds__(256) void k_zero(float* p, int count){
  int i = blockIdx.x*256 + threadIdx.x;
  if (i < count) p[i] = 0.f;
}

__global__ __launch_bounds__(256) void k_hist(const int* __restrict__ node_out,
                                              const float* __restrict__ ew,
                                              double* __restrict__ deg_pack){
  int e = blockIdx.x*256 + threadIdx.x;
  if (e < EE){
    int o = node_out[e];
    atomicAdd(&deg_pack[o], 65536.0 + (double)ew[e]);
  }
}

__global__ __launch_bounds__(256) void k_logsum(const double* __restrict__ deg_pack,
                                                float* __restrict__ logsum){
  __shared__ float sd[256];
  int t = threadIdx.x; int n = blockIdx.x*256 + t;
  float v = 0.f;
  if (n < NN) v = logf(pack_sumw(deg_pack[n]) + 1.f);
  sd[t] = v; __syncthreads();
  for (int off = 128; off > 0; off >>= 1){
    if (t < off) sd[t] += sd[t+off];
    __syncthreads();
  }
  if (t == 0) atomicAdd(logsum, sd[0]);
}

__global__ __launch_bounds__(256) void k_scan1(const double* __restrict__ deg_pack,
                                               int* __restrict__ partials){
  __shared__ int sd[256];
  int t = threadIdx.x; int n = blockIdx.x*256 + t;
  sd[t] = (n < NN) ? pack_count(deg_pack[n]) : 0; __syncthreads();
  for (int off = 128; off > 0; off >>= 1){
    if (t < off) sd[t] += sd[t+off];
    __syncthreads();
  }
  if (t == 0) partials[blockIdx.x] = sd[0];
}

__global__ __launch_bounds__(256) void k_scan2(int* __restrict__ partials, int nb,
                                               int* __restrict__ row_start,
                                               int2* __restrict__ csr){
  __shared__ int sd[256];
  int t = threadIdx.x;
  int v = (t < nb) ? partials[t] : 0;
  sd[t] = v; __syncthreads();
  for (int off = 1; off < 256; off <<= 1){
    int x = (t >= off) ? sd[t-off] : 0;
    __syncthreads();
    sd[t] += x;
    __syncthreads();
  }
  if (t < nb) partials[t] = sd[t] - v;   // exclusive
  if (t == 0) row_start[NN] = EE;
  if (t < 16) csr[EE + t] = make_int2(0, 0);   // zero the pad tail (re-poisoned each call)
}

__global__ __launch_bounds__(256) void k_scan3(const double* __restrict__ deg_pack,
                                               const int* __restrict__ partials,
                                               int* __restrict__ row_start,
                                               int* __restrict__ cursor){
  __shared__ int sd[256];
  int t = threadIdx.x; int n = blockIdx.x*256 + t;
  int v = (n < NN) ? pack_count(deg_pack[n]) : 0;
  sd[t] = v; __syncthreads();
  for (int off = 1; off < 256; off <<= 1){
    int x = (t >= off) ? sd[t-off] : 0;
    __syncthreads();
    sd[t] += x;
    __syncthreads();
  }
  if (n < NN){
    int rs = partials[blockIdx.x] + sd[t] - v;  // exclusive
    row_start[n] = rs; cursor[n] = rs;
  }
}

__global__ __launch_bounds__(256) void k_fillcsr(const int* __restrict__ node_in,
                                                 const int* __restrict__ node_out,
                                                 const float* __restrict__ ew,
                                                 int* __restrict__ cursor,
                                                 int2* __restrict__ csr){
  int e = blockIdx.x*256 + threadIdx.x;
  if (e < EE){
    int o = node_out[e];
    int pos = atomicAdd(&cursor[o], 1);
    int2 v; v.x = node_in[e]; v.y = __float_as_int(ew[e]);
    csr[pos] = v;
  }
}

__global__ __launch_bounds__(256) void k_scales(const double* __restrict__ deg_pack,
                                                const float* __restrict__ logsum,
                                                float* __restrict__ scale_arr,
                                                float* __restrict__ inv_arr){
  int n = blockIdx.x*256 + threadIdx.x;
  if (n < NN){
    float mean = *logsum / (float)NN;
    float s = logf(pack_sumw(deg_pack[n]) + 1.f) / mean;
    scale_arr[n] = s;
    inv_arr[n]   = 1.f / fmaxf(s, 0.01f);
  }
}

// rel_input per layer (6x32) and query-part of final MLP (64)
__global__ __launch_bounds__(256) void k_prep(const float* __restrict__ qw,
                                              const float* __restrict__ rel_W,
                                              const float* __restrict__ rel_b,
                                              const float* __restrict__ W1,
                                              const float* __restrict__ b1,
                                              float* __restrict__ rel6,
                                              float* __restrict__ qc){
  int t = threadIdx.x;
  if (t < 192){
    int l = t >> 5, j = t & 31;
    float s = rel_b[t];
    for (int d = 0; d < 32; ++d) s += qw[d] * rel_W[l*1024 + d*32 + j];
    rel6[t] = s;
  } else if (t < 256){
    int j = t - 192;
    float s = b1[j];
    for (int k = 0; k < 32; ++k) s += qw[k] * W1[(32+k)*64 + j];
    qc[j] = s;
  }
}

__global__ __launch_bounds__(256) void k_init_h(const int* __restrict__ hidx,
                                                float* __restrict__ h,
                                                float* __restrict__ hT){
  int i = blockIdx.x*256 + threadIdx.x;
  int hv = *hidx;
  if (i < NN*DD){
    h[i]  = ((i >> 5) == hv) ? 0.f : 100.f;   // row-major: n = i/32
    int n2 = i % NN;                           // transposed: n = i % N
    hT[i] = (n2 == hv) ? 0.f : 100.f;
  }
}

// t[n] = dot(h[n], rel_layer5) for msg_score
__global__ __launch_bounds__(256) void k_dot(const float* __restrict__ h,
                                             const float* __restrict__ rel6,
                                             float* __restrict__ tdot){
  int n0 = blockIdx.x*256 + threadIdx.x;
  int n = (n0 < NN) ? n0 : NN-1;
  const float* relr = rel6 + 5*32;
  float s = 0.f;
  #pragma unroll
  for (int d = 0; d < 32; ++d) s += h[n*32 + d] * relr[d];
  if (n0 < NN) tdot[n0] = s;
}

// ---------------- fused per-layer kernel ----------------
// Block = 64 nodes, 256 threads. LDS 32768 B. Grid is 782 blocks (~3/CU), so
// occupancy is GRID-bound: __launch_bounds__(256,3) raises the VGPR cap to
// ~170 so the 8-deep csr prefetch + 8 h-gathers stay live in registers
// (R5 post-mortem: 48 VGPRs serialized the pipeline).
// csr has 16 zeroed pad entries -> all batch loads unconditional; the
// `ee < eEnd` ACC guard keeps pads out of the accumulation.
template<bool PRED>
__global__ __launch_bounds__(256, 3) void k_layer(const float* __restrict__ h,
                                               const float* __restrict__ hT,
                                               const float* __restrict__ rel6,
                                               const int* __restrict__ row_start,
                                               const int2* __restrict__ csr,
                                               const int* __restrict__ hidx,
                                               const float* __restrict__ tdot,
                                               const float* __restrict__ lin_W,
                                               const float* __restrict__ lin_b,
                                               const float* __restrict__ scale_arr,
                                               const float* __restrict__ inv_arr,
                                               float* __restrict__ h_next,
                                               float* __restrict__ hT_next,
                                               float* __restrict__ pred_out,
                                               int l){
  __shared__ float sh[128*64];
  int tid = threadIdx.x;
  int base = blockIdx.x * 64;
  int hv0 = *hidx;

  // ---- phase 1: aggregation ----
  {
    int g = tid >> 5, lane = tid & 31;
    int ng0 = base + g*8;
    int nend = ((ng0 + 8 <= NN) ? 8 : (NN - ng0));   // nodes in this group
    if (nend > 0){
      float rel = rel6[l*32 + lane];
      auto rsv = [&](int i){ int idx = ng0 + i; return row_start[idx > NN ? NN : idx]; };
      int eBeg = rsv(0), eEnd = rsv(nend);
      // per-node end boundaries (shift-register)
      int node_end = rsv(1);
      int nb1 = rsv(2), nb2 = rsv(3), nb3 = rsv(4), nb4 = rsv(5),
          nb5 = rsv(6), nb6 = rsv(7), nb7 = rsv(8);

      int curn = ng0;
      float S1 = 0.f, S2 = 0.f, M = -INFINITY, m = INFINITY;
      float best = -INFINITY; int bi = NN;
      int dcnt = 0;

#define FINALIZE() do { \
      float bnd = (curn == hv0) ? 0.f : 100.f; \
      float mx, mn; \
      if (dcnt > 0){ \
        float em = (rel >= 0.f) ? rel*M : rel*m; \
        float en = (rel >= 0.f) ? rel*m : rel*M; \
        mx = fmaxf(em, bnd); mn = fminf(en, bnd); \
      } else { mx = bnd; mn = bnd; } \
      float cntf = (float)(dcnt + 1); \
      float mean = (rel*S1 + bnd) / cntf; \
      float sq   = (rel*rel*S2 + bnd*bnd) / cntf; \
      float sdv  = sqrtf(fmaxf(sq - mean*mean, 1e-6f)); \
      int nl = curn - base; \
      int kp0 = lane*4; \
      sh[(kp0+0)*64 + (nl ^ ( kp0   &31))] = mean; \
      sh[(kp0+1)*64 + (nl ^ ((kp0+1)&31))] = mx; \
      sh[(kp0+2)*64 + (nl ^ ((kp0+2)&31))] = mn; \
      sh[(kp0+3)*64 + (nl ^ ((kp0+3)&31))] = sdv; \
      if (PRED){ \
        float ss = (curn == hv0) ? 0.f : 3200.f; \
        if (ss > best){ best = ss; bi = curn; } \
        else if (ss == best && curn < bi) bi = curn; \
        if (lane == 0) pred_out[curn] = (float)bi; \
      } \
      S1 = 0.f; S2 = 0.f; M = -INFINITY; m = INFINITY; \
      best = -INFINITY; bi = NN; dcnt = 0; \
      ++curn; \
      node_end = nb1; nb1 = nb2; nb2 = nb3; nb3 = nb4; \
      nb4 = nb5; nb5 = nb6; nb6 = nb7; \
    } while(0)

      // unconditional loads: csr padded with 16 zero entries past EE
      int2 c0,c1,c2,c3,c4,c5,c6,c7;
      c0 = csr[eBeg+0]; c1 = csr[eBeg+1]; c2 = csr[eBeg+2]; c3 = csr[eBeg+3];
      c4 = csr[eBeg+4]; c5 = csr[eBeg+5]; c6 = csr[eBeg+6]; c7 = csr[eBeg+7];
      for (int e = eBeg; e < eEnd; e += 8){
        // gathers for current batch (8 independent, in flight together)
        float h0 = h[c0.x*32 + lane], h1 = h[c1.x*32 + lane];
        float h2 = h[c2.x*32 + lane], h3 = h[c3.x*32 + lane];
        float h4 = h[c4.x*32 + lane], h5 = h[c5.x*32 + lane];
        float h6 = h[c6.x*32 + lane], h7 = h[c7.x*32 + lane];
        float t0=0,t1=0,t2=0,t3=0,t4=0,t5=0,t6=0,t7=0;
        if (PRED){
          t0 = tdot[c0.x]; t1 = tdot[c1.x]; t2 = tdot[c2.x]; t3 = tdot[c3.x];
          t4 = tdot[c4.x]; t5 = tdot[c5.x]; t6 = tdot[c6.x]; t7 = tdot[c7.x];
        }
        // prefetch next batch's csr (unconditional; pad covers eEnd..eEnd+15)
        int en = e + 8;
        int2 p0 = csr[en+0], p1 = csr[en+1], p2 = csr[en+2], p3 = csr[en+3];
        int2 p4 = csr[en+4], p5 = csr[en+5], p6 = csr[en+6], p7 = csr[en+7];
        // accumulate (sequential order preserved; boundary walk between edges)
#define ACC(J, CJ, HJ, TJ) do { \
        int ee = e + J; \
        if (ee < eEnd){ \
          while (ee >= node_end) FINALIZE(); \
          float w = __int_as_float(CJ.y); \
          float wm = w * HJ; \
          S1 += wm; S2 += wm * HJ; \
          M = fmaxf(M, wm); m = fminf(m, wm); \
          ++dcnt; \
          if (PRED){ \
            float sv = w * TJ; \
            if (sv > best){ best = sv; bi = CJ.x; } \
            else if (sv == best && CJ.x < bi) bi = CJ.x; \
          } \
        } } while(0)
        ACC(0, c0, h0, t0); ACC(1, c1, h1, t1);
        ACC(2, c2, h2, t2); ACC(3, c3, h3, t3);
        ACC(4, c4, h4, t4); ACC(5, c5, h5, t5);
        ACC(6, c6, h6, t6); ACC(7, c7, h7, t7);
#undef ACC
        c0=p0; c1=p1; c2=p2; c3=p3; c4=p4; c5=p5; c6=p6; c7=p7;
      }
      // trailing finalizes (incl. empty nodes)
      while (curn < ng0 + nend) FINALIZE();
#undef FINALIZE
    }
  }
  __syncthreads();

  // ---- phase 2: linear ----
  {
    const float* Wl = lin_W + (size_t)l * 13312;   // 416*32
    int lane = tid & 63;
    int j0 = __builtin_amdgcn_readfirstlane((tid >> 6) * 8);  // 0,8,16,24
    int n0 = base + lane;
    int n = (n0 < NN) ? n0 : NN-1;
    float sc = scale_arr[n], iv = inv_arr[n];
    float acc[8];
    #pragma unroll
    for (int j = 0; j < 8; ++j) acc[j] = lin_b[l*32 + j0 + j];

    for (int k = 0; k < 32; ++k){
      float xv = hT[k*NN + n];
      const float* wr = Wl + k*32 + j0;
      #pragma unroll
      for (int j = 0; j < 8; ++j) acc[j] += xv * wr[j];
    }
    for (int kp = 0; kp < 128; ++kp){
      float f = sh[kp*64 + (lane ^ (kp & 31))];
      int d = kp >> 2, c = kp & 3;
      const float* wr = Wl + (32 + d*12 + c*3)*32 + j0;
      float f1 = f*sc, f2 = f*iv;
      #pragma unroll
      for (int j = 0; j < 8; ++j)
        acc[j] += f*wr[j] + f1*wr[32+j] + f2*wr[64+j];
    }

    if (n0 < NN){
      #pragma unroll
      for (int j = 0; j < 8; ++j){
        float v = fmaxf(acc[j], 0.f);
        h_next[n0*32 + j0 + j] = v;
        hT_next[(j0+j)*NN + n0] = v;
      }
    }
  }
}

// ---------------- final MLP ----------------
__global__ __launch_bounds__(256) void k_mlp(const float* __restrict__ hT,
                                             const float* __restrict__ qc,
                                             const float* __restrict__ W1,
                                             const float* __restrict__ W2,
                                             const float* __restrict__ b2,
                                             float* __restrict__ out_score){
  int n0 = blockIdx.x*256 + threadIdx.x;
  int n = (n0 < NN) ? n0 : NN-1;
  float acc[64];
  #pragma unroll
  for (int j = 0; j < 64; ++j) acc[j] = qc[j];
  for (int k = 0; k < 32; ++k){
    float xv = hT[k*NN + n];
    const float* wr = W1 + k*64;
    #pragma unroll
    for (int j = 0; j < 64; ++j) acc[j] += xv * wr[j];
  }
  float s = b2[0];
  #pragma unroll
  for (int j = 0; j < 64; ++j) s += fmaxf(acc[j], 0.f) * W2[j];
  if (n0 < NN) out_score[n0] = s;
}

// ---------------- host launch ----------------
extern "C" void kernel_launch(void* const* d_in, const int* in_sizes, int n_in,
                              void* d_out, int out_size, void* d_ws, size_t ws_size,
                              hipStream_t stream){
  const int*   node_in  = (const int*)d_in[0];
  const int*   node_out = (const int*)d_in[1];
  const float* ew       = (const float*)d_in[2];
  const int*   hidx     = (const int*)d_in[3];
  const float* qw       = (const float*)d_in[4];
  const float* rel_W    = (const float*)d_in[5];
  const float* rel_b    = (const float*)d_in[6];
  const float* lin_W    = (const float*)d_in[7];
  const float* lin_b    = (const float*)d_in[8];
  const float* W1       = (const float*)d_in[9];
  const float* b1       = (const float*)d_in[10];
  const float* W2       = (const float*)d_in[11];
  const float* b2       = (const float*)d_in[12];
  float* out_score = (float*)d_out;
  float* out_pred  = out_score + NN;

  char* w = (char*)d_ws;
  size_t off = 0;
  auto take = [&](size_t bytes)->char*{
    char* p = w + off;
    off = (off + bytes + 255) & ~(size_t)255;
    return p;
  };
  double* deg_pack = (double*)take((size_t)NN*8 + 64*4);
  float*  logsum   = (float*)(deg_pack + NN);
  int*   row_start = (int*)take((size_t)(NN+1)*4);
  int*   cursor    = (int*)take((size_t)NN*4);
  int*   partials  = (int*)take(256*4);
  float* rel6      = (float*)take(192*4);
  float* qc        = (float*)take(64*4);
  float* scale_arr = (float*)take((size_t)NN*4);
  float* inv_arr   = (float*)take((size_t)NN*4);
  float* tdot      = (float*)take((size_t)NN*4);
  int2*  csr       = (int2*)take((size_t)(EE+16)*8);
  float* h_a       = (float*)take((size_t)NN*32*4);
  float* hT_a      = (float*)take((size_t)NN*32*4);
  float* h_b       = (float*)take((size_t)NN*32*4);
  float* hT_b      = (float*)take((size_t)NN*32*4);

  int zc = 2*NN + 64;   // N doubles == 2N floats, + logsum block
  int nb = (NN + 255) / 256;   // 196
  int nlb = (NN + 63) / 64;    // 782
  k_zero   <<<(zc+255)/256, 256, 0, stream>>>((float*)deg_pack, zc);
  k_hist   <<<(EE+255)/256, 256, 0, stream>>>(node_out, ew, deg_pack);
  k_logsum <<<nb, 256, 0, stream>>>(deg_pack, logsum);
  k_scan1  <<<nb, 256, 0, stream>>>(deg_pack, partials);
  k_scan2  <<<1, 256, 0, stream>>>(partials, nb, row_start, csr);
  k_scan3  <<<nb, 256, 0, stream>>>(deg_pack, partials, row_start, cursor);
  k_fillcsr<<<(EE+255)/256, 256, 0, stream>>>(node_in, node_out, ew, cursor, csr);
  k_scales <<<nb, 256, 0, stream>>>(deg_pack, logsum, scale_arr, inv_arr);
  k_prep   <<<1, 256, 0, stream>>>(qw, rel_W, rel_b, W1, b1, rel6, qc);
  k_init_h <<<(NN*DD+255)/256, 256, 0, stream>>>(hidx, h_a, hT_a);

  float* hc = h_a;  float* hTc = hT_a;
  float* hn = h_b;  float* hTn = hT_b;
  for (int l = 0; l < 6; ++l){
    if (l == 5){
      k_dot<<<nb, 256, 0, stream>>>(hc, rel6, tdot);
      k_layer<true><<<nlb, 256, 0, stream>>>(hc, hTc, rel6, row_start, csr,
                                             hidx, tdot, lin_W, lin_b,
                                             scale_arr, inv_arr, hn, hTn,
                                             out_pred, l);
    } else {
      k_layer<false><<<nlb, 256, 0, stream>>>(hc, hTc, rel6, row_start, csr,
                                              hidx, tdot, lin_W, lin_b,
                                              scale_arr, inv_arr, hn, hTn,
                                              out_pred, l);
    }
    float* t1 = hc;  hc = hn;  hn = t1;
    float* t2 = hTc; hTc = hTn; hTn = t2;
  }
  k_mlp<<<nb, 256, 0, stream>>>(hTc, qc, W1, W2, b2, out_score);
}